// Round 5
// baseline (293.038 us; speedup 1.0000x reference)
//
#include <hip/hip_runtime.h>
#include <math.h>

#define BB   8
#define CIN  512
#define NSP  2304
#define OCH  640   // 64(q)+64(k)+512(v)
#define LL   48

typedef __attribute__((ext_vector_type(8))) short bf16x8;
typedef __attribute__((ext_vector_type(8))) unsigned short u16x8;
typedef __attribute__((ext_vector_type(4))) float f32x4;

__device__ inline unsigned short f2bf(float f) {
  unsigned int u = __float_as_uint(f);
  unsigned int r = (u + 0x7fffu + ((u >> 16) & 1u)) >> 16;   // RNE
  return (unsigned short)r;
}
__device__ inline float bf2f(unsigned short h) {
  return __uint_as_float(((unsigned int)h) << 16);
}

// stage a 128-row x 64-col bf16 tile (row stride LD elements) into LDS linear
// [128][64]; requires in-scope: w (wave id 0..3), colb, rsub
#define STAGE128x64(GP, LD, LDSN)                                              \
  {                                                                            \
    const unsigned short* gsrc_ = (GP);                                        \
    _Pragma("unroll") for (int cc_ = 0; cc_ < 4; cc_++) {                      \
      int base_ = w * 2048 + cc_ * 512;                                        \
      int row_ = w * 32 + cc_ * 8 + rsub;                                      \
      __builtin_amdgcn_global_load_lds(                                        \
          (const __attribute__((address_space(1))) void*)(gsrc_ +              \
              (size_t)row_ * (LD) + colb),                                     \
          (__attribute__((address_space(3))) void*)&(LDSN)[base_], 16, 0, 0);  \
    }                                                                          \
  }

// one K=64 step on a 128x128 tile from APTR/BPTR; needs lane, wr, wc, acc
#define MFMA_STEP(APTR, BPTR)                                                  \
  _Pragma("unroll") for (int kk_ = 0; kk_ < 2; kk_++) {                        \
    bf16x8 af_[4], bf_[4];                                                     \
    int kcol_ = kk_ * 32 + (lane >> 4) * 8;                                    \
    _Pragma("unroll") for (int m_ = 0; m_ < 4; m_++)                           \
      af_[m_] = *(const bf16x8*)&(APTR)[(wr * 64 + m_ * 16 + (lane & 15)) * 64 + kcol_]; \
    _Pragma("unroll") for (int n_ = 0; n_ < 4; n_++)                           \
      bf_[n_] = *(const bf16x8*)&(BPTR)[(wc * 64 + n_ * 16 + (lane & 15)) * 64 + kcol_]; \
    _Pragma("unroll") for (int m_ = 0; m_ < 4; m_++)                           \
      _Pragma("unroll") for (int n_ = 0; n_ < 4; n_++)                         \
        acc[m_][n_] = __builtin_amdgcn_mfma_f32_16x16x32_bf16(                 \
            af_[m_], bf_[n_], acc[m_][n_], 0, 0, 0);                           \
  }

#define MFMA_PROLOG()                                                          \
  const int tid = threadIdx.x;                                                 \
  const int lane = tid & 63;                                                   \
  const int w = tid >> 6;                                                      \
  const int wr = w >> 1, wc = w & 1;                                           \
  const int colb = (lane & 7) * 8;                                             \
  const int rsub = lane >> 3;                                                  \
  f32x4 acc[4][4] = {};                                                        \
  (void)colb; (void)rsub;

// ---------------------------------------------------------------------------
// merged: stack W -> bf16 + bias, and build Pcat bf16
__global__ __launch_bounds__(256) void prep_all(
    const float* __restrict__ Wq, const float* __restrict__ bq,
    const float* __restrict__ Wk, const float* __restrict__ bk,
    const float* __restrict__ Wv, const float* __restrict__ bv,
    const float* __restrict__ rel_rows, const float* __restrict__ rel_cols,
    unsigned short* __restrict__ Wstb, float* __restrict__ bst,
    unsigned short* __restrict__ Pcatb) {
  int idx = blockIdx.x * 256 + threadIdx.x;
  if (idx < OCH * CIN) {
    int row = idx >> 9;
    float val;
    if (row < 64)       val = Wq[idx];
    else if (row < 128) val = Wk[idx - (64 << 9)];
    else                val = Wv[idx - (128 << 9)];
    Wstb[idx] = f2bf(val);
    if (idx < OCH) {
      float bval;
      if (idx < 64)       bval = bq[idx];
      else if (idx < 128) bval = bk[idx - 64];
      else                bval = bv[idx - 128];
      bst[idx] = bval;
    }
  } else {
    int p = idx - OCH * CIN;          // < 128*2304
    int dd = p / NSP;
    int n = p - dd * NSP;
    int xr = n / LL;
    int ic = n - xr * LL;
    int shift = ic - xr + (LL - 1);
    float val = (dd < 64) ? rel_rows[shift * 64 + dd]
                          : rel_cols[shift * 64 + (dd - 64)];
    Pcatb[p] = f2bf(val);
  }
}

// x [b][c][n] fp32 -> xTb [b][n][c] bf16
__global__ __launch_bounds__(256) void transpose_x(
    const float* __restrict__ x, unsigned short* __restrict__ xTb) {
  __shared__ float t[64][65];
  const int n0 = blockIdx.x * 64;
  const int c0 = blockIdx.y * 64;
  const int b = blockIdx.z;
  const int j = threadIdx.x & 63;
  const int g = threadIdx.x >> 6;
  const float* xp = x + (size_t)b * CIN * NSP;
#pragma unroll
  for (int i = 0; i < 16; i++) {
    int cl = g * 16 + i;
    t[cl][j] = xp[(size_t)(c0 + cl) * NSP + n0 + j];
  }
  __syncthreads();
  unsigned short* op = xTb + (size_t)b * NSP * CIN;
#pragma unroll
  for (int i = 0; i < 16; i++) {
    int nl = g * 16 + i;
    op[(size_t)(n0 + nl) * CIN + c0 + j] = f2bf(t[j][nl]);
  }
}

// ---------------------------------------------------------------------------
// proj (2-phase dbuf): y16 = bf16(W @ xT + b); emits BN partial sums
__global__ __launch_bounds__(256) void proj_mfma(
    const unsigned short* __restrict__ Wstb, const float* __restrict__ bst,
    const unsigned short* __restrict__ xTb, unsigned short* __restrict__ y16,
    float* __restrict__ part1, float* __restrict__ part2) {
  __shared__ unsigned short As[2][8192];
  __shared__ unsigned short Bs[2][8192];
  int sw = ((blockIdx.x & 7) * 90) + (blockIdx.x >> 3);   // 720 wg
  const int rb = sw % 5;
  const int nb = (sw / 5) % 18;
  const int b = sw / 90;
  const int r0 = rb * 128;
  const int n0 = nb * 128;
  MFMA_PROLOG();
  const unsigned short* A = Wstb + (size_t)r0 * CIN;
  const unsigned short* B = xTb + (size_t)b * NSP * CIN + (size_t)n0 * CIN;
  int cur = 0;
  STAGE128x64(A, CIN, As[0]);
  STAGE128x64(B, CIN, Bs[0]);
  __syncthreads();
  for (int t = 0; t < 7; ++t) {
    STAGE128x64(A + (t + 1) * 64, CIN, As[cur ^ 1]);
    STAGE128x64(B + (t + 1) * 64, CIN, Bs[cur ^ 1]);
    MFMA_STEP(As[cur], Bs[cur]);
    __syncthreads();
    cur ^= 1;
  }
  MFMA_STEP(As[cur], Bs[cur]);
  __syncthreads();    // before LDS scratch reuse
  float* sp = (float*)&As[0][0];   // [128][2] s1 then [128][2] s2
#pragma unroll
  for (int m = 0; m < 4; m++) {
#pragma unroll
    for (int r = 0; r < 4; r++) {
      int rl = wr * 64 + m * 16 + (lane >> 4) * 4 + r;
      int row = r0 + rl;
      float bias = bst[row];
      float s1 = 0.f, s2 = 0.f;
#pragma unroll
      for (int n = 0; n < 4; n++) {
        float yv = acc[m][n][r] + bias;
        s1 += yv;
        s2 += yv * yv;
        y16[((size_t)b * OCH + row) * NSP + n0 + wc * 64 + n * 16 + (lane & 15)] = f2bf(yv);
      }
#pragma unroll
      for (int off = 1; off < 16; off <<= 1) {
        s1 += __shfl_xor(s1, off);
        s2 += __shfl_xor(s2, off);
      }
      if ((lane & 15) == 0) {
        sp[rl * 2 + wc] = s1;
        sp[256 + rl * 2 + wc] = s2;
      }
    }
  }
  __syncthreads();
  if (tid < 128) {
    size_t pbase = ((size_t)b * 18 + nb) * OCH + r0 + tid;
    part1[pbase] = sp[tid * 2] + sp[tid * 2 + 1];
    part2[pbase] = sp[256 + tid * 2] + sp[256 + tid * 2 + 1];
  }
}

// reduce 144 partials/channel -> chanA/chanB
__global__ __launch_bounds__(256) void bn_finalize(
    const float* __restrict__ part1, const float* __restrict__ part2,
    const float* __restrict__ qs_, const float* __restrict__ qb_,
    const float* __restrict__ ks_, const float* __restrict__ kb_,
    const float* __restrict__ vs_, const float* __restrict__ vb_,
    float* __restrict__ chanA, float* __restrict__ chanB) {
  const int ch = blockIdx.x;
  const int tid = threadIdx.x;
  float s1 = 0.f, s2 = 0.f;
  for (int t = tid; t < 144; t += 256) {
    s1 += part1[(size_t)t * OCH + ch];
    s2 += part2[(size_t)t * OCH + ch];
  }
  __shared__ float sb[8];
#pragma unroll
  for (int off = 32; off > 0; off >>= 1) {
    s1 += __shfl_down(s1, off);
    s2 += __shfl_down(s2, off);
  }
  int lane = tid & 63, wid = tid >> 6;
  if (lane == 0) { sb[wid] = s1; sb[4 + wid] = s2; }
  __syncthreads();
  if (tid == 0) {
    float ts  = sb[0] + sb[1] + sb[2] + sb[3];
    float ts2 = sb[4] + sb[5] + sb[6] + sb[7];
    const float inv = 1.f / (float)(BB * NSP);
    float mean = ts * inv;
    float var  = ts2 * inv - mean * mean;
    float scale, bias;
    if (ch < 64)       { scale = qs_[ch];       bias = qb_[ch]; }
    else if (ch < 128) { scale = ks_[ch - 64];  bias = kb_[ch - 64]; }
    else               { scale = vs_[ch - 128]; bias = vb_[ch - 128]; }
    float a = scale * rsqrtf(var + 1e-5f);
    chanA[ch] = a;
    chanB[ch] = bias - mean * a;
  }
}

// in-place affine+relu on all of y16 (bf16)
__global__ __launch_bounds__(256) void bnrelu_all(
    unsigned short* __restrict__ y16, const float* __restrict__ chanA,
    const float* __restrict__ chanB) {
  size_t i = ((size_t)blockIdx.x * 256 + threadIdx.x) * 8;
  int ch = (int)((i / NSP) % OCH);
  float a = chanA[ch], bo = chanB[ch];
  ushort4 u0 = *(ushort4*)&y16[i];
  ushort4 u1 = *(ushort4*)&y16[i + 4];
  ushort4 o0, o1;
  o0.x = f2bf(fmaxf(0.f, a * bf2f(u0.x) + bo));
  o0.y = f2bf(fmaxf(0.f, a * bf2f(u0.y) + bo));
  o0.z = f2bf(fmaxf(0.f, a * bf2f(u0.z) + bo));
  o0.w = f2bf(fmaxf(0.f, a * bf2f(u0.w) + bo));
  o1.x = f2bf(fmaxf(0.f, a * bf2f(u1.x) + bo));
  o1.y = f2bf(fmaxf(0.f, a * bf2f(u1.y) + bo));
  o1.z = f2bf(fmaxf(0.f, a * bf2f(u1.z) + bo));
  o1.w = f2bf(fmaxf(0.f, a * bf2f(u1.w) + bo));
  *(ushort4*)&y16[i] = o0;
  *(ushort4*)&y16[i + 4] = o1;
}

// q/k channels [d][n] -> qTb/kTb [n][d], LDS-tiled, post-relu
__global__ __launch_bounds__(256) void tr_qk(
    const unsigned short* __restrict__ y16, unsigned short* __restrict__ qTb,
    unsigned short* __restrict__ kTb) {
  __shared__ unsigned short t[64][72];
  const int n0 = blockIdx.x * 64;
  const int qk = blockIdx.y;          // 0=q, 1=k
  const int b = blockIdx.z;
  const int j = threadIdx.x & 63;
  const int g = threadIdx.x >> 6;
#pragma unroll
  for (int i = 0; i < 16; i++) {
    int cl = g * 16 + i;
    t[cl][j] = y16[((size_t)b * OCH + qk * 64 + cl) * NSP + n0 + j];
  }
  __syncthreads();
  unsigned short* out = (qk == 0) ? qTb : kTb;
#pragma unroll
  for (int i = 0; i < 16; i++) {
    int nl = g * 16 + i;
    out[((size_t)b * NSP + n0 + nl) * 64 + j] = t[j][nl];
  }
}

// qs[b,d] = sum_n q[b,d,n] (post-relu, from y16)
__global__ __launch_bounds__(256) void qsum_kernel(
    const unsigned short* __restrict__ y16, float* __restrict__ qs) {
  int bd = blockIdx.x;
  int b = bd >> 6, d = bd & 63;
  const ushort4* p = (const ushort4*)(y16 + ((size_t)b * OCH + d) * NSP);
  float s = 0.f;
  for (int t = threadIdx.x; t < NSP / 4; t += 256) {
    ushort4 u = p[t];
    s += bf2f(u.x) + bf2f(u.y) + bf2f(u.z) + bf2f(u.w);
  }
  __shared__ float sb[4];
#pragma unroll
  for (int off = 32; off > 0; off >>= 1) s += __shfl_down(s, off);
  int lane = threadIdx.x & 63, wid = threadIdx.x >> 6;
  if (lane == 0) sb[wid] = s;
  __syncthreads();
  if (threadIdx.x == 0) qs[bd] = sb[0] + sb[1] + sb[2] + sb[3];
}

// Gqp[b*4+kc][d][e] = partial sum over k-chunk of q[d,i]*q[e,i]
__global__ __launch_bounds__(256) void gq_mfma(
    const unsigned short* __restrict__ y16, float* __restrict__ Gqp) {
  __shared__ float wlds[4 * 4096];
  const int bx = blockIdx.x;          // 32
  const int b = bx >> 2, kc = bx & 3;
  const int tid = threadIdx.x;
  const int lane = tid & 63;
  const int w = tid >> 6;
  const unsigned short* q = y16 + (size_t)b * OCH * NSP;
  f32x4 acc[4][4] = {};
  for (int k0 = kc * 576 + w * 32; k0 < (kc + 1) * 576; k0 += 128) {
    bf16x8 fr[4];
#pragma unroll
    for (int f = 0; f < 4; f++) {
      int row = f * 16 + (lane & 15);
      fr[f] = *(const bf16x8*)&q[(size_t)row * NSP + k0 + (lane >> 4) * 8];
    }
#pragma unroll
    for (int fm = 0; fm < 4; fm++)
#pragma unroll
      for (int fn = 0; fn < 4; fn++)
        acc[fm][fn] = __builtin_amdgcn_mfma_f32_16x16x32_bf16(
            fr[fm], fr[fn], acc[fm][fn], 0, 0, 0);
  }
#pragma unroll
  for (int fm = 0; fm < 4; fm++)
#pragma unroll
    for (int fn = 0; fn < 4; fn++)
#pragma unroll
      for (int r = 0; r < 4; r++) {
        int d = fm * 16 + (lane >> 4) * 4 + r;
        int e = fn * 16 + (lane & 15);
        wlds[w * 4096 + d * 64 + e] = acc[fm][fn][r];
      }
  __syncthreads();
  for (int t = tid; t < 4096; t += 256)
    Gqp[(size_t)bx * 4096 + t] =
        wlds[t] + wlds[4096 + t] + wlds[8192 + t] + wlds[12288 + t];
}

// ---------------------------------------------------------------------------
// energy+exp: Pp[b,i,j] = bf16(exp(qT[i]·kT[j])); coalesced via LDS repack;
// also per-row partial sums
__global__ __launch_bounds__(256) void energy_mfma(
    const unsigned short* __restrict__ qTb, const unsigned short* __restrict__ kTb,
    unsigned short* __restrict__ Pp, float* __restrict__ Ppart) {
  __shared__ unsigned short lds[16384];    // 32KB: As | Bs, then repack tile
  __shared__ float rs[256];
  int sw = ((blockIdx.x & 7) * 324) + (blockIdx.x >> 3);   // 2592 wg
  const int jb = sw % 18;
  const int ib = (sw / 18) % 18;
  const int b = sw / 324;
  const int i0 = ib * 128;
  const int j0 = jb * 128;
  MFMA_PROLOG();
  STAGE128x64(qTb + ((size_t)b * NSP + i0) * 64, 64, lds);
  STAGE128x64(kTb + ((size_t)b * NSP + j0) * 64, 64, (lds + 8192));
  __syncthreads();
  MFMA_STEP(lds, (lds + 8192));
  __syncthreads();   // all waves done reading As/Bs before repack overwrite
#pragma unroll
  for (int m = 0; m < 4; m++) {
#pragma unroll
    for (int r = 0; r < 4; r++) {
      int rl = wr * 64 + m * 16 + (lane >> 4) * 4 + r;
      float s1 = 0.f;
#pragma unroll
      for (int n = 0; n < 4; n++) {
        unsigned short h = f2bf(__expf(acc[m][n][r]));
        lds[rl * 128 + wc * 64 + n * 16 + (lane & 15)] = h;
        s1 += bf2f(h);
      }
#pragma unroll
      for (int off = 1; off < 16; off <<= 1) s1 += __shfl_xor(s1, off);
      if ((lane & 15) == 0) rs[rl * 2 + wc] = s1;
    }
  }
  __syncthreads();
  unsigned short* pp = Pp + (size_t)b * NSP * NSP;
#pragma unroll
  for (int c8 = tid; c8 < 2048; c8 += 256) {
    int il = c8 >> 4;
    int jl = (c8 & 15) * 8;
    u16x8 v = *(const u16x8*)&lds[il * 128 + jl];
    *(u16x8*)&pp[(size_t)(i0 + il) * NSP + j0 + jl] = v;
  }
  if (tid < 128)
    Ppart[((size_t)b * 18 + jb) * NSP + i0 + tid] = rs[tid * 2] + rs[tid * 2 + 1];
}

// rZ[row] = 1/sum_jb Ppart
__global__ __launch_bounds__(256) void zred_kernel(
    const float* __restrict__ Ppart, float* __restrict__ rZ) {
  int row = blockIdx.x * 256 + threadIdx.x;   // B*NSP
  int b = row / NSP, i = row % NSP;
  float s = 0.f;
#pragma unroll
  for (int jb = 0; jb < 18; jb++) s += Ppart[((size_t)b * 18 + jb) * NSP + i];
  rZ[row] = 1.f / s;
}

// ---------------------------------------------------------------------------
// Upart[kc][b][c][dd] = partial over k-chunk of v[c,n]*Pcat[dd,n]  (2-phase)
__global__ __launch_bounds__(256) void up_mfma(
    const unsigned short* __restrict__ y16, const unsigned short* __restrict__ Pcatb,
    float* __restrict__ Upart) {
  __shared__ unsigned short As[2][8192];
  __shared__ unsigned short Bs[2][8192];
  int sw = ((blockIdx.x & 7) * 24) + (blockIdx.x >> 3);   // 192 wg
  const int cb = sw % 4;
  const int kc = (sw / 4) % 6;
  const int b = sw / 24;
  const int c0 = cb * 128;
  MFMA_PROLOG();
  const unsigned short* A = y16 + ((size_t)b * OCH + 128 + c0) * NSP + kc * 384;
  const unsigned short* B = Pcatb + kc * 384;
  int cur = 0;
  STAGE128x64(A, NSP, As[0]);
  STAGE128x64(B, NSP, Bs[0]);
  __syncthreads();
  for (int t = 0; t < 5; ++t) {
    STAGE128x64(A + (t + 1) * 64, NSP, As[cur ^ 1]);
    STAGE128x64(B + (t + 1) * 64, NSP, Bs[cur ^ 1]);
    MFMA_STEP(As[cur], Bs[cur]);
    __syncthreads();
    cur ^= 1;
  }
  MFMA_STEP(As[cur], Bs[cur]);
  float* up = Upart + ((size_t)kc * BB + b) * CIN * 128 + (size_t)c0 * 128;
#pragma unroll
  for (int m = 0; m < 4; m++)
#pragma unroll
    for (int r = 0; r < 4; r++) {
      int rl = wr * 64 + m * 16 + (lane >> 4) * 4 + r;
#pragma unroll
      for (int n = 0; n < 4; n++) {
        int col = wc * 64 + n * 16 + (lane & 15);
        up[(size_t)rl * 128 + col] = acc[m][n][r];
      }
    }
}

__global__ __launch_bounds__(256) void up_reduce(
    const float* __restrict__ Upart, float* __restrict__ Ucat) {
  size_t idx = (size_t)blockIdx.x * 256 + threadIdx.x;   // 524288
  float s = 0.f;
#pragma unroll
  for (int kc = 0; kc < 6; kc++) s += Upart[(size_t)kc * 524288 + idx];
  Ucat[idx] = s;
}

// closed-form BN stats for Eh/Ew from Ucat ([0:64]=h, [64:128]=w)
__global__ __launch_bounds__(64) void rel_stats(
    const float* __restrict__ Ucat, const float* __restrict__ Gqp,
    const float* __restrict__ qs,
    const float* __restrict__ bnr_s, const float* __restrict__ bnr_b,
    const float* __restrict__ bnc_s, const float* __restrict__ bnc_b,
    float* __restrict__ gh, float* __restrict__ gw, float* __restrict__ offc) {
  const int c = blockIdx.x;
  const int d = threadIdx.x;
  __shared__ float su[2][64];
  float s1h = 0.f, s2h = 0.f, s1w = 0.f, s2w = 0.f;
  for (int b = 0; b < BB; b++) {
    size_t base = ((size_t)b * CIN + c) * 128;
    float uh = Ucat[base + d];
    float uw = Ucat[base + 64 + d];
    __syncthreads();
    su[0][d] = uh;
    su[1][d] = uw;
    __syncthreads();
    float th = 0.f, tw = 0.f;
#pragma unroll
    for (int kc = 0; kc < 4; kc++) {
      const float* G = Gqp + ((size_t)(b * 4 + kc)) * 4096 + d * 64;
      for (int e = 0; e < 64; e++) {
        float g = G[e];
        th += g * su[0][e];
        tw += g * su[1][e];
      }
    }
    float qsd = qs[b * 64 + d];
    s1h += uh * qsd;
    s2h += uh * th;
    s1w += uw * qsd;
    s2w += uw * tw;
  }
#pragma unroll
  for (int off = 32; off > 0; off >>= 1) {
    s1h += __shfl_down(s1h, off);
    s2h += __shfl_down(s2h, off);
    s1w += __shfl_down(s1w, off);
    s2w += __shfl_down(s2w, off);
  }
  if (d == 0) {
    const float inv = 1.f / (float)(BB * NSP);
    float mh = s1h * inv, vh = s2h * inv - mh * mh;
    float mw = s1w * inv, vw = s2w * inv - mw * mw;
    float gch = bnr_s[c] * rsqrtf(vh + 1e-5f);
    float gcw = bnc_s[c] * rsqrtf(vw + 1e-5f);
    gh[c] = gch;
    gw[c] = gcw;
    offc[c] = (bnr_b[c] - mh * gch) + (bnc_b[c] - mw * gcw);
  }
}

__global__ __launch_bounds__(256) void combine_u(
    const float* __restrict__ Ucat, const float* __restrict__ gh,
    const float* __restrict__ gw, unsigned short* __restrict__ Ucb) {
  int idx = blockIdx.x * 256 + threadIdx.x;  // B*512*64
  int d = idx & 63;
  int c = (idx >> 6) & 511;
  int b = idx >> 15;
  size_t base = ((size_t)b * CIN + c) * 128;
  Ucb[idx] = f2bf(Ucat[base + d] * gh[c] + Ucat[base + 64 + d] * gw[c]);
}

// ---------------------------------------------------------------------------
// fused (2-phase dbuf): dst[c,i] = gamma*( rZ[i]*sum_j v[c,j]*Pp[i,j]
//                         + sum_d Ucb[c,d]*qT[i,d] + offc[c] ) + x[c,i]
__global__ __launch_bounds__(256) void attn_fused_gemm(
    const unsigned short* __restrict__ y16,   // v at channel offset 128
    const unsigned short* __restrict__ Pp,
    const float* __restrict__ rZ,
    const unsigned short* __restrict__ Ucb,
    const unsigned short* __restrict__ qTb,
    const float* __restrict__ offc,
    const float* __restrict__ gammap,
    const float* __restrict__ x,
    float* __restrict__ dst) {
  __shared__ unsigned short As[2][8192];
  __shared__ unsigned short Bs[2][8192];
  int sw = ((blockIdx.x & 7) * 72) + (blockIdx.x >> 3);   // 576 wg
  const int cb = sw % 4;
  const int ib = (sw / 4) % 18;
  const int b = sw / 72;
  const int c0 = cb * 128;
  const int i0 = ib * 128;
  MFMA_PROLOG();
  const unsigned short* A = y16 + ((size_t)b * OCH + 128 + c0) * NSP;
  const unsigned short* B = Pp + (size_t)b * NSP * NSP + (size_t)i0 * NSP;

  int cur = 0;
  STAGE128x64(A, NSP, As[0]);
  STAGE128x64(B, NSP, Bs[0]);
  __syncthreads();
  for (int t = 0; t < 36; ++t) {
    if (t < 35) {
      STAGE128x64(A + (t + 1) * 64, NSP, As[cur ^ 1]);
      STAGE128x64(B + (t + 1) * 64, NSP, Bs[cur ^ 1]);
    } else {
      STAGE128x64(Ucb + (size_t)b * CIN * 64 + (size_t)c0 * 64, 64, As[cur ^ 1]);
      STAGE128x64(qTb + (size_t)b * NSP * 64 + (size_t)i0 * 64, 64, Bs[cur ^ 1]);
    }
    MFMA_STEP(As[cur], Bs[cur]);
    __syncthreads();
    cur ^= 1;
  }

  // per-column softmax normalization (applies only to the V*P' part)
#pragma unroll
  for (int n = 0; n < 4; n++) {
    float rz = rZ[(size_t)b * NSP + i0 + wc * 64 + n * 16 + (lane & 15)];
#pragma unroll
    for (int m = 0; m < 4; m++)
#pragma unroll
      for (int r = 0; r < 4; r++) acc[m][n][r] *= rz;
  }

  // rank-64 rel-position tile (already staged)
  MFMA_STEP(As[cur], Bs[cur]);

  const float gmm = gammap[0];
  const float* xp = x + (size_t)b * CIN * NSP;
  float* dp = dst + (size_t)b * CIN * NSP;
#pragma unroll
  for (int m = 0; m < 4; m++) {
#pragma unroll
    for (int r = 0; r < 4; r++) {
      int c = c0 + wr * 64 + m * 16 + (lane >> 4) * 4 + r;
      float off = offc[c];
#pragma unroll
      for (int n = 0; n < 4; n++) {
        int i = i0 + wc * 64 + n * 16 + (lane & 15);
        size_t o = (size_t)c * NSP + i;
        dp[o] = gmm * (acc[m][n][r] + off) + xp[o];
      }
    }
  }
}

// ---------------------------------------------------------------------------
extern "C" void kernel_launch(void* const* d_in, const int* in_sizes, int n_in,
                              void* d_out, int out_size, void* d_ws, size_t ws_size,
                              hipStream_t stream) {
  const float* x        = (const float*)d_in[0];
  const float* Wq       = (const float*)d_in[1];
  const float* bq       = (const float*)d_in[2];
  const float* q_scale  = (const float*)d_in[3];
  const float* q_bias   = (const float*)d_in[4];
  const float* Wk       = (const float*)d_in[5];
  const float* bk       = (const float*)d_in[6];
  const float* k_scale  = (const float*)d_in[7];
  const float* k_bias   = (const float*)d_in[8];
  const float* Wv       = (const float*)d_in[9];
  const float* bv       = (const float*)d_in[10];
  const float* v_scale  = (const float*)d_in[11];
  const float* v_bias   = (const float*)d_in[12];
  const float* rel_rows = (const float*)d_in[13];
  const float* rel_cols = (const float*)d_in[14];
  const float* bnr_s    = (const float*)d_in[15];
  const float* bnr_b    = (const float*)d_in[16];
  const float* bnc_s    = (const float*)d_in[17];
  const float* bnc_b    = (const float*)d_in[18];
  const float* gamma    = (const float*)d_in[19];
  float* dst = (float*)d_out;

  float* ws = (float*)d_ws;
  size_t o = 0;
  unsigned short* Wstb = (unsigned short*)(ws + o); o += (size_t)OCH * CIN / 2;
  float* bst    = ws + o; o += 1024;
  float* chanA  = ws + o; o += 1024;
  float* chanB  = ws + o; o += 1024;
  unsigned short* Pcatb = (unsigned short*)(ws + o); o += (size_t)128 * NSP / 2;
  unsigned short* y16 = (unsigned short*)(ws + o); o += (size_t)BB * OCH * NSP / 2;
  unsigned short* xTb = (unsigned short*)(ws + o); o += (size_t)BB * NSP * CIN / 2;
  unsigned short* Pp  = (unsigned short*)(ws + o); o += (size_t)BB * NSP * NSP / 2;
  float* Ppart  = ws + o; o += (size_t)BB * 18 * NSP;
  float* rZ     = ws + o; o += (size_t)BB * NSP;
  float* Upart  = ws + o; o += (size_t)6 * BB * CIN * 128;
  float* Ucat   = ws + o; o += (size_t)BB * CIN * 128;
  float* Gqp    = ws + o; o += (size_t)32 * 4096;
  float* part1  = ws + o; o += (size_t)BB * 18 * OCH;
  float* part2  = ws + o; o += (size_t)BB * 18 * OCH;
  float* qs     = ws + o; o += 1024;
  float* gh     = ws + o; o += 1024;
  float* gw     = ws + o; o += 1024;
  float* offc   = ws + o; o += 1024;
  unsigned short* qTb = (unsigned short*)(ws + o); o += (size_t)BB * NSP * 64 / 2;
  unsigned short* kTb = (unsigned short*)(ws + o); o += (size_t)BB * NSP * 64 / 2;
  unsigned short* Ucb = (unsigned short*)(ws + o); o += (size_t)BB * CIN * 64 / 2;

  prep_all<<<(OCH * CIN + 128 * NSP) / 256, 256, 0, stream>>>(
      Wq, bq, Wk, bk, Wv, bv, rel_rows, rel_cols, Wstb, bst, Pcatb);
  transpose_x<<<dim3(NSP / 64, CIN / 64, BB), 256, 0, stream>>>(x, xTb);

  proj_mfma<<<720, 256, 0, stream>>>(Wstb, bst, xTb, y16, part1, part2);
  bn_finalize<<<OCH, 256, 0, stream>>>(part1, part2, q_scale, q_bias, k_scale,
                                       k_bias, v_scale, v_bias, chanA, chanB);
  bnrelu_all<<<(int)((size_t)BB * OCH * NSP / 8 / 256), 256, 0, stream>>>(y16, chanA, chanB);
  tr_qk<<<dim3(NSP / 64, 2, BB), 256, 0, stream>>>(y16, qTb, kTb);
  qsum_kernel<<<BB * 64, 256, 0, stream>>>(y16, qs);
  gq_mfma<<<32, 256, 0, stream>>>(y16, Gqp);

  energy_mfma<<<2592, 256, 0, stream>>>(qTb, kTb, Pp, Ppart);
  zred_kernel<<<BB * NSP / 256, 256, 0, stream>>>(Ppart, rZ);

  up_mfma<<<192, 256, 0, stream>>>(y16, Pcatb, Upart);
  up_reduce<<<2048, 256, 0, stream>>>(Upart, Ucat);
  rel_stats<<<CIN, 64, 0, stream>>>(Ucat, Gqp, qs, bnr_s, bnr_b, bnc_s, bnc_b,
                                    gh, gw, offc);
  combine_u<<<(BB * CIN * 64) / 256, 256, 0, stream>>>(Ucat, gh, gw, Ucb);

  attn_fused_gemm<<<576, 256, 0, stream>>>(y16, Pp, rZ, Ucb, qTb, offc, gamma, x, dst);
}

// Round 6
// 249.809 us; speedup vs baseline: 1.1730x; 1.1730x over previous
//
#include <hip/hip_runtime.h>
#include <math.h>

#define BB   8
#define CIN  512
#define NSP  2304
#define OCH  640   // 64(q)+64(k)+512(v)
#define LL   48

typedef __attribute__((ext_vector_type(8))) short bf16x8;
typedef __attribute__((ext_vector_type(8))) unsigned short u16x8;
typedef __attribute__((ext_vector_type(4))) float f32x4;

__device__ inline unsigned short f2bf(float f) {
  unsigned int u = __float_as_uint(f);
  unsigned int r = (u + 0x7fffu + ((u >> 16) & 1u)) >> 16;   // RNE
  return (unsigned short)r;
}
__device__ inline float bf2f(unsigned short h) {
  return __uint_as_float(((unsigned int)h) << 16);
}

// ---------------------------------------------------------------------------
// T2 swizzle (rule #21: linear LDS dest + inverse-swizzled global SOURCE +
// swizzled READ). LDS tile [128 rows][8 slots of 16B]:
//   LDS[row][slot] = G[row][slot ^ (row&7)]
// STAGE: lane (slot = lane&7, row&7 = rsub) loads G col ((lane&7)^rsub)*8 elems.
// READ of G[row][s] -> LDS[row][s ^ (row&7)]; frag rows have row&7 == lane&7.

#define STAGE128x64(GP, LD, LDSN)                                              \
  {                                                                            \
    const unsigned short* gsrc_ = (GP);                                        \
    _Pragma("unroll") for (int cc_ = 0; cc_ < 4; cc_++) {                      \
      int base_ = w * 2048 + cc_ * 512;                                        \
      int row_ = w * 32 + cc_ * 8 + rsub;                                      \
      __builtin_amdgcn_global_load_lds(                                        \
          (const __attribute__((address_space(1))) void*)(gsrc_ +              \
              (size_t)row_ * (LD) + scolb),                                    \
          (__attribute__((address_space(3))) void*)&(LDSN)[base_], 16, 0, 0);  \
    }                                                                          \
  }

// one K=64 step on a 128x128 tile from APTR/BPTR (swizzled read)
#define MFMA_STEP(APTR, BPTR)                                                  \
  _Pragma("unroll") for (int kk_ = 0; kk_ < 2; kk_++) {                        \
    bf16x8 af_[4], bf_[4];                                                     \
    int kcol_ = (((kk_ * 4 + (lane >> 4)) ^ (lane & 7)) * 8);                  \
    _Pragma("unroll") for (int m_ = 0; m_ < 4; m_++)                           \
      af_[m_] = *(const bf16x8*)&(APTR)[(wr * 64 + m_ * 16 + (lane & 15)) * 64 + kcol_]; \
    _Pragma("unroll") for (int n_ = 0; n_ < 4; n_++)                           \
      bf_[n_] = *(const bf16x8*)&(BPTR)[(wc * 64 + n_ * 16 + (lane & 15)) * 64 + kcol_]; \
    _Pragma("unroll") for (int m_ = 0; m_ < 4; m_++)                           \
      _Pragma("unroll") for (int n_ = 0; n_ < 4; n_++)                         \
        acc[m_][n_] = __builtin_amdgcn_mfma_f32_16x16x32_bf16(                 \
            af_[m_], bf_[n_], acc[m_][n_], 0, 0, 0);                           \
  }

#define MFMA_PROLOG()                                                          \
  const int tid = threadIdx.x;                                                 \
  const int lane = tid & 63;                                                   \
  const int w = tid >> 6;                                                      \
  const int wr = w >> 1, wc = w & 1;                                           \
  const int rsub = lane >> 3;                                                  \
  const int scolb = ((lane & 7) ^ rsub) * 8;                                   \
  f32x4 acc[4][4] = {};                                                        \
  (void)scolb; (void)rsub;

// ---------------------------------------------------------------------------
// merged: stack W -> bf16 + bias, and build Pcat bf16
__global__ __launch_bounds__(256) void prep_all(
    const float* __restrict__ Wq, const float* __restrict__ bq,
    const float* __restrict__ Wk, const float* __restrict__ bk,
    const float* __restrict__ Wv, const float* __restrict__ bv,
    const float* __restrict__ rel_rows, const float* __restrict__ rel_cols,
    unsigned short* __restrict__ Wstb, float* __restrict__ bst,
    unsigned short* __restrict__ Pcatb) {
  int idx = blockIdx.x * 256 + threadIdx.x;
  if (idx < OCH * CIN) {
    int row = idx >> 9;
    float val;
    if (row < 64)       val = Wq[idx];
    else if (row < 128) val = Wk[idx - (64 << 9)];
    else                val = Wv[idx - (128 << 9)];
    Wstb[idx] = f2bf(val);
    if (idx < OCH) {
      float bval;
      if (idx < 64)       bval = bq[idx];
      else if (idx < 128) bval = bk[idx - 64];
      else                bval = bv[idx - 128];
      bst[idx] = bval;
    }
  } else {
    int p = idx - OCH * CIN;          // < 128*2304
    int dd = p / NSP;
    int n = p - dd * NSP;
    int xr = n / LL;
    int ic = n - xr * LL;
    int shift = ic - xr + (LL - 1);
    float val = (dd < 64) ? rel_rows[shift * 64 + dd]
                          : rel_cols[shift * 64 + (dd - 64)];
    Pcatb[p] = f2bf(val);
  }
}

// x [b][c][n] fp32 -> xTb [b][n][c] bf16
__global__ __launch_bounds__(256) void transpose_x(
    const float* __restrict__ x, unsigned short* __restrict__ xTb) {
  __shared__ float t[64][65];
  const int n0 = blockIdx.x * 64;
  const int c0 = blockIdx.y * 64;
  const int b = blockIdx.z;
  const int j = threadIdx.x & 63;
  const int g = threadIdx.x >> 6;
  const float* xp = x + (size_t)b * CIN * NSP;
#pragma unroll
  for (int i = 0; i < 16; i++) {
    int cl = g * 16 + i;
    t[cl][j] = xp[(size_t)(c0 + cl) * NSP + n0 + j];
  }
  __syncthreads();
  unsigned short* op = xTb + (size_t)b * NSP * CIN;
#pragma unroll
  for (int i = 0; i < 16; i++) {
    int nl = g * 16 + i;
    op[(size_t)(n0 + nl) * CIN + c0 + j] = f2bf(t[j][nl]);
  }
}

// ---------------------------------------------------------------------------
// proj (round-4 single-buffer + swizzle): y16 = bf16(W @ xT + b); BN partials
__global__ __launch_bounds__(256) void proj_mfma(
    const unsigned short* __restrict__ Wstb, const float* __restrict__ bst,
    const unsigned short* __restrict__ xTb, unsigned short* __restrict__ y16,
    float* __restrict__ part1, float* __restrict__ part2) {
  __shared__ unsigned short As[8192];
  __shared__ unsigned short Bs[8192];
  int sw = ((blockIdx.x & 7) * 90) + (blockIdx.x >> 3);   // 720 wg
  const int rb = sw % 5;
  const int nb = (sw / 5) % 18;
  const int b = sw / 90;
  const int r0 = rb * 128;
  const int n0 = nb * 128;
  MFMA_PROLOG();
  const unsigned short* A = Wstb + (size_t)r0 * CIN;
  const unsigned short* B = xTb + (size_t)b * NSP * CIN + (size_t)n0 * CIN;
  for (int k0 = 0; k0 < CIN; k0 += 64) {
    STAGE128x64(A + k0, CIN, As);
    STAGE128x64(B + k0, CIN, Bs);
    __syncthreads();
    MFMA_STEP(As, Bs);
    __syncthreads();
  }
  float* sp = (float*)As;   // [128][2] s1 then [128][2] s2
#pragma unroll
  for (int m = 0; m < 4; m++) {
#pragma unroll
    for (int r = 0; r < 4; r++) {
      int rl = wr * 64 + m * 16 + (lane >> 4) * 4 + r;
      int row = r0 + rl;
      float bias = bst[row];
      float s1 = 0.f, s2 = 0.f;
#pragma unroll
      for (int n = 0; n < 4; n++) {
        float yv = acc[m][n][r] + bias;
        s1 += yv;
        s2 += yv * yv;
        y16[((size_t)b * OCH + row) * NSP + n0 + wc * 64 + n * 16 + (lane & 15)] = f2bf(yv);
      }
#pragma unroll
      for (int off = 1; off < 16; off <<= 1) {
        s1 += __shfl_xor(s1, off);
        s2 += __shfl_xor(s2, off);
      }
      if ((lane & 15) == 0) {
        sp[rl * 2 + wc] = s1;
        sp[256 + rl * 2 + wc] = s2;
      }
    }
  }
  __syncthreads();
  if (tid < 128) {
    size_t pbase = ((size_t)b * 18 + nb) * OCH + r0 + tid;
    part1[pbase] = sp[tid * 2] + sp[tid * 2 + 1];
    part2[pbase] = sp[256 + tid * 2] + sp[256 + tid * 2 + 1];
  }
}

// reduce 144 partials/channel -> chanA/chanB
__global__ __launch_bounds__(256) void bn_finalize(
    const float* __restrict__ part1, const float* __restrict__ part2,
    const float* __restrict__ qs_, const float* __restrict__ qb_,
    const float* __restrict__ ks_, const float* __restrict__ kb_,
    const float* __restrict__ vs_, const float* __restrict__ vb_,
    float* __restrict__ chanA, float* __restrict__ chanB) {
  const int ch = blockIdx.x;
  const int tid = threadIdx.x;
  float s1 = 0.f, s2 = 0.f;
  for (int t = tid; t < 144; t += 256) {
    s1 += part1[(size_t)t * OCH + ch];
    s2 += part2[(size_t)t * OCH + ch];
  }
  __shared__ float sb[8];
#pragma unroll
  for (int off = 32; off > 0; off >>= 1) {
    s1 += __shfl_down(s1, off);
    s2 += __shfl_down(s2, off);
  }
  int lane = tid & 63, wid = tid >> 6;
  if (lane == 0) { sb[wid] = s1; sb[4 + wid] = s2; }
  __syncthreads();
  if (tid == 0) {
    float ts  = sb[0] + sb[1] + sb[2] + sb[3];
    float ts2 = sb[4] + sb[5] + sb[6] + sb[7];
    const float inv = 1.f / (float)(BB * NSP);
    float mean = ts * inv;
    float var  = ts2 * inv - mean * mean;
    float scale, bias;
    if (ch < 64)       { scale = qs_[ch];       bias = qb_[ch]; }
    else if (ch < 128) { scale = ks_[ch - 64];  bias = kb_[ch - 64]; }
    else               { scale = vs_[ch - 128]; bias = vb_[ch - 128]; }
    float a = scale * rsqrtf(var + 1e-5f);
    chanA[ch] = a;
    chanB[ch] = bias - mean * a;
  }
}

// in-place affine+relu on all of y16 (bf16)
__global__ __launch_bounds__(256) void bnrelu_all(
    unsigned short* __restrict__ y16, const float* __restrict__ chanA,
    const float* __restrict__ chanB) {
  size_t i = ((size_t)blockIdx.x * 256 + threadIdx.x) * 8;
  int ch = (int)((i / NSP) % OCH);
  float a = chanA[ch], bo = chanB[ch];
  ushort4 u0 = *(ushort4*)&y16[i];
  ushort4 u1 = *(ushort4*)&y16[i + 4];
  ushort4 o0, o1;
  o0.x = f2bf(fmaxf(0.f, a * bf2f(u0.x) + bo));
  o0.y = f2bf(fmaxf(0.f, a * bf2f(u0.y) + bo));
  o0.z = f2bf(fmaxf(0.f, a * bf2f(u0.z) + bo));
  o0.w = f2bf(fmaxf(0.f, a * bf2f(u0.w) + bo));
  o1.x = f2bf(fmaxf(0.f, a * bf2f(u1.x) + bo));
  o1.y = f2bf(fmaxf(0.f, a * bf2f(u1.y) + bo));
  o1.z = f2bf(fmaxf(0.f, a * bf2f(u1.z) + bo));
  o1.w = f2bf(fmaxf(0.f, a * bf2f(u1.w) + bo));
  *(ushort4*)&y16[i] = o0;
  *(ushort4*)&y16[i + 4] = o1;
}

// q/k channels [d][n] -> qTb/kTb [n][d], LDS-tiled, post-relu
__global__ __launch_bounds__(256) void tr_qk(
    const unsigned short* __restrict__ y16, unsigned short* __restrict__ qTb,
    unsigned short* __restrict__ kTb) {
  __shared__ unsigned short t[64][72];
  const int n0 = blockIdx.x * 64;
  const int qk = blockIdx.y;          // 0=q, 1=k
  const int b = blockIdx.z;
  const int j = threadIdx.x & 63;
  const int g = threadIdx.x >> 6;
#pragma unroll
  for (int i = 0; i < 16; i++) {
    int cl = g * 16 + i;
    t[cl][j] = y16[((size_t)b * OCH + qk * 64 + cl) * NSP + n0 + j];
  }
  __syncthreads();
  unsigned short* out = (qk == 0) ? qTb : kTb;
#pragma unroll
  for (int i = 0; i < 16; i++) {
    int nl = g * 16 + i;
    out[((size_t)b * NSP + n0 + nl) * 64 + j] = t[j][nl];
  }
}

// qs[b,d] = sum_n q[b,d,n] (post-relu, from y16)
__global__ __launch_bounds__(256) void qsum_kernel(
    const unsigned short* __restrict__ y16, float* __restrict__ qs) {
  int bd = blockIdx.x;
  int b = bd >> 6, d = bd & 63;
  const ushort4* p = (const ushort4*)(y16 + ((size_t)b * OCH + d) * NSP);
  float s = 0.f;
  for (int t = threadIdx.x; t < NSP / 4; t += 256) {
    ushort4 u = p[t];
    s += bf2f(u.x) + bf2f(u.y) + bf2f(u.z) + bf2f(u.w);
  }
  __shared__ float sb[4];
#pragma unroll
  for (int off = 32; off > 0; off >>= 1) s += __shfl_down(s, off);
  int lane = threadIdx.x & 63, wid = threadIdx.x >> 6;
  if (lane == 0) sb[wid] = s;
  __syncthreads();
  if (threadIdx.x == 0) qs[bd] = sb[0] + sb[1] + sb[2] + sb[3];
}

// Gqp[b*4+kc][d][e] = partial sum over k-chunk of q[d,i]*q[e,i]
__global__ __launch_bounds__(256) void gq_mfma(
    const unsigned short* __restrict__ y16, float* __restrict__ Gqp) {
  __shared__ float wlds[4 * 4096];
  const int bx = blockIdx.x;          // 32
  const int b = bx >> 2, kc = bx & 3;
  const int tid = threadIdx.x;
  const int lane = tid & 63;
  const int w = tid >> 6;
  const unsigned short* q = y16 + (size_t)b * OCH * NSP;
  f32x4 acc[4][4] = {};
  for (int k0 = kc * 576 + w * 32; k0 < (kc + 1) * 576; k0 += 128) {
    bf16x8 fr[4];
#pragma unroll
    for (int f = 0; f < 4; f++) {
      int row = f * 16 + (lane & 15);
      fr[f] = *(const bf16x8*)&q[(size_t)row * NSP + k0 + (lane >> 4) * 8];
    }
#pragma unroll
    for (int fm = 0; fm < 4; fm++)
#pragma unroll
      for (int fn = 0; fn < 4; fn++)
        acc[fm][fn] = __builtin_amdgcn_mfma_f32_16x16x32_bf16(
            fr[fm], fr[fn], acc[fm][fn], 0, 0, 0);
  }
#pragma unroll
  for (int fm = 0; fm < 4; fm++)
#pragma unroll
    for (int fn = 0; fn < 4; fn++)
#pragma unroll
      for (int r = 0; r < 4; r++) {
        int d = fm * 16 + (lane >> 4) * 4 + r;
        int e = fn * 16 + (lane & 15);
        wlds[w * 4096 + d * 64 + e] = acc[fm][fn][r];
      }
  __syncthreads();
  for (int t = tid; t < 4096; t += 256)
    Gqp[(size_t)bx * 4096 + t] =
        wlds[t] + wlds[4096 + t] + wlds[8192 + t] + wlds[12288 + t];
}

// ---------------------------------------------------------------------------
// energy+exp (round-4 direct-store + swizzle): Pp = bf16(exp(qT·kT^T)) + partials
__global__ __launch_bounds__(256) void energy_mfma(
    const unsigned short* __restrict__ qTb, const unsigned short* __restrict__ kTb,
    unsigned short* __restrict__ Pp, float* __restrict__ Ppart) {
  __shared__ unsigned short As[8192];
  __shared__ unsigned short Bs[8192];
  int sw = ((blockIdx.x & 7) * 324) + (blockIdx.x >> 3);   // 2592 wg
  const int jb = sw % 18;
  const int ib = (sw / 18) % 18;
  const int b = sw / 324;
  const int i0 = ib * 128;
  const int j0 = jb * 128;
  MFMA_PROLOG();
  STAGE128x64(qTb + ((size_t)b * NSP + i0) * 64, 64, As);
  STAGE128x64(kTb + ((size_t)b * NSP + j0) * 64, 64, Bs);
  __syncthreads();
  MFMA_STEP(As, Bs);
  __syncthreads();
  float* sp = (float*)As;
  unsigned short* pp = Pp + (size_t)b * NSP * NSP;
#pragma unroll
  for (int m = 0; m < 4; m++) {
#pragma unroll
    for (int r = 0; r < 4; r++) {
      int rl = wr * 64 + m * 16 + (lane >> 4) * 4 + r;
      int i = i0 + rl;
      float s1 = 0.f;
#pragma unroll
      for (int n = 0; n < 4; n++) {
        int j = j0 + wc * 64 + n * 16 + (lane & 15);
        unsigned short h = f2bf(__expf(acc[m][n][r]));
        pp[(size_t)i * NSP + j] = h;
        s1 += bf2f(h);
      }
#pragma unroll
      for (int off = 1; off < 16; off <<= 1) s1 += __shfl_xor(s1, off);
      if ((lane & 15) == 0) sp[rl * 2 + wc] = s1;
    }
  }
  __syncthreads();
  if (tid < 128)
    Ppart[((size_t)b * 18 + jb) * NSP + i0 + tid] = sp[tid * 2] + sp[tid * 2 + 1];
}

// rZ[row] = 1/sum_jb Ppart
__global__ __launch_bounds__(256) void zred_kernel(
    const float* __restrict__ Ppart, float* __restrict__ rZ) {
  int row = blockIdx.x * 256 + threadIdx.x;   // B*NSP
  int b = row / NSP, i = row % NSP;
  float s = 0.f;
#pragma unroll
  for (int jb = 0; jb < 18; jb++) s += Ppart[((size_t)b * 18 + jb) * NSP + i];
  rZ[row] = 1.f / s;
}

// ---------------------------------------------------------------------------
// Upart (round-4 single-buffer + swizzle)
__global__ __launch_bounds__(256) void up_mfma(
    const unsigned short* __restrict__ y16, const unsigned short* __restrict__ Pcatb,
    float* __restrict__ Upart) {
  __shared__ unsigned short As[8192];
  __shared__ unsigned short Bs[8192];
  int sw = ((blockIdx.x & 7) * 24) + (blockIdx.x >> 3);   // 192 wg
  const int cb = sw % 4;
  const int kc = (sw / 4) % 6;
  const int b = sw / 24;
  const int c0 = cb * 128;
  MFMA_PROLOG();
  const unsigned short* A = y16 + ((size_t)b * OCH + 128 + c0) * NSP;
  for (int k0 = kc * 384; k0 < kc * 384 + 384; k0 += 64) {
    STAGE128x64(A + k0, NSP, As);
    STAGE128x64(Pcatb + k0, NSP, Bs);
    __syncthreads();
    MFMA_STEP(As, Bs);
    __syncthreads();
  }
  float* up = Upart + ((size_t)kc * BB + b) * CIN * 128 + (size_t)c0 * 128;
#pragma unroll
  for (int m = 0; m < 4; m++)
#pragma unroll
    for (int r = 0; r < 4; r++) {
      int rl = wr * 64 + m * 16 + (lane >> 4) * 4 + r;
#pragma unroll
      for (int n = 0; n < 4; n++) {
        int col = wc * 64 + n * 16 + (lane & 15);
        up[(size_t)rl * 128 + col] = acc[m][n][r];
      }
    }
}

__global__ __launch_bounds__(256) void up_reduce(
    const float* __restrict__ Upart, float* __restrict__ Ucat) {
  size_t idx = (size_t)blockIdx.x * 256 + threadIdx.x;   // 524288
  float s = 0.f;
#pragma unroll
  for (int kc = 0; kc < 6; kc++) s += Upart[(size_t)kc * 524288 + idx];
  Ucat[idx] = s;
}

// closed-form BN stats for Eh/Ew from Ucat ([0:64]=h, [64:128]=w)
__global__ __launch_bounds__(64) void rel_stats(
    const float* __restrict__ Ucat, const float* __restrict__ Gqp,
    const float* __restrict__ qs,
    const float* __restrict__ bnr_s, const float* __restrict__ bnr_b,
    const float* __restrict__ bnc_s, const float* __restrict__ bnc_b,
    float* __restrict__ gh, float* __restrict__ gw, float* __restrict__ offc) {
  const int c = blockIdx.x;
  const int d = threadIdx.x;
  __shared__ float su[2][64];
  float s1h = 0.f, s2h = 0.f, s1w = 0.f, s2w = 0.f;
  for (int b = 0; b < BB; b++) {
    size_t base = ((size_t)b * CIN + c) * 128;
    float uh = Ucat[base + d];
    float uw = Ucat[base + 64 + d];
    __syncthreads();
    su[0][d] = uh;
    su[1][d] = uw;
    __syncthreads();
    float th = 0.f, tw = 0.f;
#pragma unroll
    for (int kc = 0; kc < 4; kc++) {
      const float* G = Gqp + ((size_t)(b * 4 + kc)) * 4096 + d * 64;
      for (int e = 0; e < 64; e++) {
        float g = G[e];
        th += g * su[0][e];
        tw += g * su[1][e];
      }
    }
    float qsd = qs[b * 64 + d];
    s1h += uh * qsd;
    s2h += uh * th;
    s1w += uw * qsd;
    s2w += uw * tw;
  }
#pragma unroll
  for (int off = 32; off > 0; off >>= 1) {
    s1h += __shfl_down(s1h, off);
    s2h += __shfl_down(s2h, off);
    s1w += __shfl_down(s1w, off);
    s2w += __shfl_down(s2w, off);
  }
  if (d == 0) {
    const float inv = 1.f / (float)(BB * NSP);
    float mh = s1h * inv, vh = s2h * inv - mh * mh;
    float mw = s1w * inv, vw = s2w * inv - mw * mw;
    float gch = bnr_s[c] * rsqrtf(vh + 1e-5f);
    float gcw = bnc_s[c] * rsqrtf(vw + 1e-5f);
    gh[c] = gch;
    gw[c] = gcw;
    offc[c] = (bnr_b[c] - mh * gch) + (bnc_b[c] - mw * gcw);
  }
}

__global__ __launch_bounds__(256) void combine_u(
    const float* __restrict__ Ucat, const float* __restrict__ gh,
    const float* __restrict__ gw, unsigned short* __restrict__ Ucb) {
  int idx = blockIdx.x * 256 + threadIdx.x;  // B*512*64
  int d = idx & 63;
  int c = (idx >> 6) & 511;
  int b = idx >> 15;
  size_t base = ((size_t)b * CIN + c) * 128;
  Ucb[idx] = f2bf(Ucat[base + d] * gh[c] + Ucat[base + 64 + d] * gw[c]);
}

// ---------------------------------------------------------------------------
// fused (lookahead-2 pipeline, counted vmcnt, raw barriers, T2 swizzle, T5):
// dst[c,i] = gamma*( rZ[i]*sum_j v[c,j]*Pp[i,j] + sum_d Ucb[c,d]*qT[i,d]
//                  + offc[c] ) + x[c,i]
__global__ __launch_bounds__(256) void attn_fused_gemm(
    const unsigned short* __restrict__ y16,   // v at channel offset 128
    const unsigned short* __restrict__ Pp,
    const float* __restrict__ rZ,
    const unsigned short* __restrict__ Ucb,
    const unsigned short* __restrict__ qTb,
    const float* __restrict__ offc,
    const float* __restrict__ gammap,
    const float* __restrict__ x,
    float* __restrict__ dst) {
  __shared__ unsigned short As[2][8192];
  __shared__ unsigned short Bs[2][8192];
  int sw = ((blockIdx.x & 7) * 72) + (blockIdx.x >> 3);   // 576 wg
  const int cb = sw % 4;
  const int ib = (sw / 4) % 18;
  const int b = sw / 72;
  const int c0 = cb * 128;
  const int i0 = ib * 128;
  MFMA_PROLOG();
  const unsigned short* A = y16 + ((size_t)b * OCH + 128 + c0) * NSP;
  const unsigned short* B = Pp + (size_t)b * NSP * NSP + (size_t)i0 * NSP;
  const unsigned short* A2 = Ucb + (size_t)b * CIN * 64 + (size_t)c0 * 64;
  const unsigned short* B2 = qTb + (size_t)b * NSP * 64 + (size_t)i0 * 64;

  // prologue: stage tiles 0 and 1 (8 loads each)
  STAGE128x64(A, NSP, As[0]);
  STAGE128x64(B, NSP, Bs[0]);
  STAGE128x64(A + 64, NSP, As[1]);
  STAGE128x64(B + 64, NSP, Bs[1]);
  asm volatile("s_waitcnt vmcnt(8)" ::: "memory");   // tile 0 landed
  __builtin_amdgcn_sched_barrier(0);
  __builtin_amdgcn_s_barrier();

  int cur = 0;
  // tiles 0..35 = main K (Pp), tile 36 = rank-64 rel tile
  for (int tt = 0; tt < 37; ++tt) {
    if (tt == 36) {
      // softmax normalization applies only to the V*P' accumulation
#pragma unroll
      for (int n = 0; n < 4; n++) {
        float rz = rZ[(size_t)b * NSP + i0 + wc * 64 + n * 16 + (lane & 15)];
#pragma unroll
        for (int m = 0; m < 4; m++)
#pragma unroll
          for (int r = 0; r < 4; r++) acc[m][n][r] *= rz;
      }
    }
    __builtin_amdgcn_s_setprio(1);
    MFMA_STEP(As[cur], Bs[cur]);
    __builtin_amdgcn_s_setprio(0);
    __builtin_amdgcn_sched_barrier(0);
    __builtin_amdgcn_s_barrier();                    // reads of buf[cur] done
    if (tt + 2 < 36) {
      STAGE128x64(A + (tt + 2) * 64, NSP, As[cur]);
      STAGE128x64(B + (tt + 2) * 64, NSP, Bs[cur]);
      asm volatile("s_waitcnt vmcnt(8)" ::: "memory");   // tile tt+1 landed
    } else if (tt + 2 == 36) {
      STAGE128x64(A2, 64, As[cur]);
      STAGE128x64(B2, 64, Bs[cur]);
      asm volatile("s_waitcnt vmcnt(8)" ::: "memory");
    } else {
      asm volatile("s_waitcnt vmcnt(0)" ::: "memory");   // tail drain
    }
    __builtin_amdgcn_sched_barrier(0);
    __builtin_amdgcn_s_barrier();                    // buf[cur^1] ready for all
    cur ^= 1;
  }

  const float gmm = gammap[0];
  const float* xp = x + (size_t)b * CIN * NSP;
  float* dp = dst + (size_t)b * CIN * NSP;
#pragma unroll
  for (int m = 0; m < 4; m++) {
#pragma unroll
    for (int r = 0; r < 4; r++) {
      int c = c0 + wr * 64 + m * 16 + (lane >> 4) * 4 + r;
      float off = offc[c];
#pragma unroll
      for (int n = 0; n < 4; n++) {
        int i = i0 + wc * 64 + n * 16 + (lane & 15);
        size_t o = (size_t)c * NSP + i;
        dp[o] = gmm * (acc[m][n][r] + off) + xp[o];
      }
    }
  }
}

// ---------------------------------------------------------------------------
extern "C" void kernel_launch(void* const* d_in, const int* in_sizes, int n_in,
                              void* d_out, int out_size, void* d_ws, size_t ws_size,
                              hipStream_t stream) {
  const float* x        = (const float*)d_in[0];
  const float* Wq       = (const float*)d_in[1];
  const float* bq       = (const float*)d_in[2];
  const float* q_scale  = (const float*)d_in[3];
  const float* q_bias   = (const float*)d_in[4];
  const float* Wk       = (const float*)d_in[5];
  const float* bk       = (const float*)d_in[6];
  const float* k_scale  = (const float*)d_in[7];
  const float* k_bias   = (const float*)d_in[8];
  const float* Wv       = (const float*)d_in[9];
  const float* bv       = (const float*)d_in[10];
  const float* v_scale  = (const float*)d_in[11];
  const float* v_bias   = (const float*)d_in[12];
  const float* rel_rows = (const float*)d_in[13];
  const float* rel_cols = (const float*)d_in[14];
  const float* bnr_s    = (const float*)d_in[15];
  const float* bnr_b    = (const float*)d_in[16];
  const float* bnc_s    = (const float*)d_in[17];
  const float* bnc_b    = (const float*)d_in[18];
  const float* gamma    = (const float*)d_in[19];
  float* dst = (float*)d_out;

  float* ws = (float*)d_ws;
  size_t o = 0;
  unsigned short* Wstb = (unsigned short*)(ws + o); o += (size_t)OCH * CIN / 2;
  float* bst    = ws + o; o += 1024;
  float* chanA  = ws + o; o += 1024;
  float* chanB  = ws + o; o += 1024;
  unsigned short* Pcatb = (unsigned short*)(ws + o); o += (size_t)128 * NSP / 2;
  unsigned short* y16 = (unsigned short*)(ws + o); o += (size_t)BB * OCH * NSP / 2;
  unsigned short* xTb = (unsigned short*)(ws + o); o += (size_t)BB * NSP * CIN / 2;
  unsigned short* Pp  = (unsigned short*)(ws + o); o += (size_t)BB * NSP * NSP / 2;
  float* Ppart  = ws + o; o += (size_t)BB * 18 * NSP;
  float* rZ     = ws + o; o += (size_t)BB * NSP;
  float* Upart  = ws + o; o += (size_t)6 * BB * CIN * 128;
  float* Ucat   = ws + o; o += (size_t)BB * CIN * 128;
  float* Gqp    = ws + o; o += (size_t)32 * 4096;
  float* part1  = ws + o; o += (size_t)BB * 18 * OCH;
  float* part2  = ws + o; o += (size_t)BB * 18 * OCH;
  float* qs     = ws + o; o += 1024;
  float* gh     = ws + o; o += 1024;
  float* gw     = ws + o; o += 1024;
  float* offc   = ws + o; o += 1024;
  unsigned short* qTb = (unsigned short*)(ws + o); o += (size_t)BB * NSP * 64 / 2;
  unsigned short* kTb = (unsigned short*)(ws + o); o += (size_t)BB * NSP * 64 / 2;
  unsigned short* Ucb = (unsigned short*)(ws + o); o += (size_t)BB * CIN * 64 / 2;

  prep_all<<<(OCH * CIN + 128 * NSP) / 256, 256, 0, stream>>>(
      Wq, bq, Wk, bk, Wv, bv, rel_rows, rel_cols, Wstb, bst, Pcatb);
  transpose_x<<<dim3(NSP / 64, CIN / 64, BB), 256, 0, stream>>>(x, xTb);

  proj_mfma<<<720, 256, 0, stream>>>(Wstb, bst, xTb, y16, part1, part2);
  bn_finalize<<<OCH, 256, 0, stream>>>(part1, part2, q_scale, q_bias, k_scale,
                                       k_bias, v_scale, v_bias, chanA, chanB);
  bnrelu_all<<<(int)((size_t)BB * OCH * NSP / 8 / 256), 256, 0, stream>>>(y16, chanA, chanB);
  tr_qk<<<dim3(NSP / 64, 2, BB), 256, 0, stream>>>(y16, qTb, kTb);
  qsum_kernel<<<BB * 64, 256, 0, stream>>>(y16, qs);
  gq_mfma<<<32, 256, 0, stream>>>(y16, Gqp);

  energy_mfma<<<2592, 256, 0, stream>>>(qTb, kTb, Pp, Ppart);
  zred_kernel<<<BB * NSP / 256, 256, 0, stream>>>(Ppart, rZ);

  up_mfma<<<192, 256, 0, stream>>>(y16, Pcatb, Upart);
  up_reduce<<<2048, 256, 0, stream>>>(Upart, Ucat);
  rel_stats<<<CIN, 64, 0, stream>>>(Ucat, Gqp, qs, bnr_s, bnr_b, bnc_s, bnc_b,
                                    gh, gw, offc);
  combine_u<<<(BB * CIN * 64) / 256, 256, 0, stream>>>(Ucat, gh, gw, Ucb);

  attn_fused_gemm<<<576, 256, 0, stream>>>(y16, Pp, rZ, Ucb, qTb, offc, gamma, x, dst);
}

// Round 7
// 237.926 us; speedup vs baseline: 1.2316x; 1.0499x over previous
//
#include <hip/hip_runtime.h>
#include <math.h>

#define BB   8
#define CIN  512
#define NSP  2304
#define OCH  640   // 64(q)+64(k)+512(v)
#define LL   48

typedef __attribute__((ext_vector_type(8))) short bf16x8;
typedef __attribute__((ext_vector_type(8))) unsigned short u16x8;
typedef __attribute__((ext_vector_type(4))) float f32x4;

__device__ inline unsigned short f2bf(float f) {
  unsigned int u = __float_as_uint(f);
  unsigned int r = (u + 0x7fffu + ((u >> 16) & 1u)) >> 16;   // RNE
  return (unsigned short)r;
}
__device__ inline float bf2f(unsigned short h) {
  return __uint_as_float(((unsigned int)h) << 16);
}

// ---------------------------------------------------------------------------
// T2 swizzle (rule #21): linear LDS dest + inverse-swizzled global SOURCE +
// swizzled READ. LDS[row][slot16B] = G[row][slot ^ (row&7)].

#define STAGE128x64(GP, LD, LDSN)                                              \
  {                                                                            \
    const unsigned short* gsrc_ = (GP);                                        \
    _Pragma("unroll") for (int cc_ = 0; cc_ < 4; cc_++) {                      \
      int base_ = w * 2048 + cc_ * 512;                                        \
      int row_ = w * 32 + cc_ * 8 + rsub;                                      \
      __builtin_amdgcn_global_load_lds(                                        \
          (const __attribute__((address_space(1))) void*)(gsrc_ +              \
              (size_t)row_ * (LD) + scolb),                                    \
          (__attribute__((address_space(3))) void*)&(LDSN)[base_], 16, 0, 0);  \
    }                                                                          \
  }

// 8-wave role-split stage: waves 0-3 stage A tile, waves 4-7 stage B tile.
// each wave issues exactly 4 global_load_lds.
#define STAGE8(GPA, LDA, LA, GPB, LDB, LB)                                     \
  {                                                                            \
    if (w < 4) {                                                               \
      const unsigned short* gsrc_ = (GPA);                                     \
      _Pragma("unroll") for (int cc_ = 0; cc_ < 4; cc_++) {                    \
        int base_ = w * 2048 + cc_ * 512;                                      \
        int row_ = w * 32 + cc_ * 8 + rsub;                                    \
        __builtin_amdgcn_global_load_lds(                                      \
            (const __attribute__((address_space(1))) void*)(gsrc_ +            \
                (size_t)row_ * (LDA) + scolb),                                 \
            (__attribute__((address_space(3))) void*)&(LA)[base_], 16, 0, 0);  \
      }                                                                        \
    } else {                                                                   \
      const unsigned short* gsrc_ = (GPB);                                     \
      int w2_ = w - 4;                                                         \
      _Pragma("unroll") for (int cc_ = 0; cc_ < 4; cc_++) {                    \
        int base_ = w2_ * 2048 + cc_ * 512;                                    \
        int row_ = w2_ * 32 + cc_ * 8 + rsub;                                  \
        __builtin_amdgcn_global_load_lds(                                      \
            (const __attribute__((address_space(1))) void*)(gsrc_ +            \
                (size_t)row_ * (LDB) + scolb),                                 \
            (__attribute__((address_space(3))) void*)&(LB)[base_], 16, 0, 0);  \
      }                                                                        \
    }                                                                          \
  }

// one K=64 step, 4-wave (2x2), 64x64 per wave; acc[4][4]
#define MFMA_STEP(APTR, BPTR)                                                  \
  _Pragma("unroll") for (int kk_ = 0; kk_ < 2; kk_++) {                        \
    bf16x8 af_[4], bf_[4];                                                     \
    int kcol_ = (((kk_ * 4 + (lane >> 4)) ^ (lane & 7)) * 8);                  \
    _Pragma("unroll") for (int m_ = 0; m_ < 4; m_++)                           \
      af_[m_] = *(const bf16x8*)&(APTR)[(wr * 64 + m_ * 16 + (lane & 15)) * 64 + kcol_]; \
    _Pragma("unroll") for (int n_ = 0; n_ < 4; n_++)                           \
      bf_[n_] = *(const bf16x8*)&(BPTR)[(wc * 64 + n_ * 16 + (lane & 15)) * 64 + kcol_]; \
    _Pragma("unroll") for (int m_ = 0; m_ < 4; m_++)                           \
      _Pragma("unroll") for (int n_ = 0; n_ < 4; n_++)                         \
        acc[m_][n_] = __builtin_amdgcn_mfma_f32_16x16x32_bf16(                 \
            af_[m_], bf_[n_], acc[m_][n_], 0, 0, 0);                           \
  }

// one K=64 step, 8-wave (2x4), 64x32 per wave; acc[4][2]
#define MFMA_STEP8(APTR, BPTR)                                                 \
  _Pragma("unroll") for (int kk_ = 0; kk_ < 2; kk_++) {                        \
    bf16x8 af_[4], bf_[2];                                                     \
    int kcol_ = (((kk_ * 4 + (lane >> 4)) ^ (lane & 7)) * 8);                  \
    _Pragma("unroll") for (int m_ = 0; m_ < 4; m_++)                           \
      af_[m_] = *(const bf16x8*)&(APTR)[(wr * 64 + m_ * 16 + (lane & 15)) * 64 + kcol_]; \
    _Pragma("unroll") for (int n_ = 0; n_ < 2; n_++)                           \
      bf_[n_] = *(const bf16x8*)&(BPTR)[(wc * 32 + n_ * 16 + (lane & 15)) * 64 + kcol_]; \
    _Pragma("unroll") for (int m_ = 0; m_ < 4; m_++)                           \
      _Pragma("unroll") for (int n_ = 0; n_ < 2; n_++)                         \
        acc[m_][n_] = __builtin_amdgcn_mfma_f32_16x16x32_bf16(                 \
            af_[m_], bf_[n_], acc[m_][n_], 0, 0, 0);                           \
  }

#define MFMA_PROLOG()                                                          \
  const int tid = threadIdx.x;                                                 \
  const int lane = tid & 63;                                                   \
  const int w = tid >> 6;                                                      \
  const int wr = w >> 1, wc = w & 1;                                           \
  const int rsub = lane >> 3;                                                  \
  const int scolb = ((lane & 7) ^ rsub) * 8;                                   \
  f32x4 acc[4][4] = {};                                                        \
  (void)scolb; (void)rsub; (void)wr; (void)wc;

// ---------------------------------------------------------------------------
__global__ __launch_bounds__(256) void prep_all(
    const float* __restrict__ Wq, const float* __restrict__ bq,
    const float* __restrict__ Wk, const float* __restrict__ bk,
    const float* __restrict__ Wv, const float* __restrict__ bv,
    const float* __restrict__ rel_rows, const float* __restrict__ rel_cols,
    unsigned short* __restrict__ Wstb, float* __restrict__ bst,
    unsigned short* __restrict__ Pcatb) {
  int idx = blockIdx.x * 256 + threadIdx.x;
  if (idx < OCH * CIN) {
    int row = idx >> 9;
    float val;
    if (row < 64)       val = Wq[idx];
    else if (row < 128) val = Wk[idx - (64 << 9)];
    else                val = Wv[idx - (128 << 9)];
    Wstb[idx] = f2bf(val);
    if (idx < OCH) {
      float bval;
      if (idx < 64)       bval = bq[idx];
      else if (idx < 128) bval = bk[idx - 64];
      else                bval = bv[idx - 128];
      bst[idx] = bval;
    }
  } else {
    int p = idx - OCH * CIN;          // < 128*2304
    int dd = p / NSP;
    int n = p - dd * NSP;
    int xr = n / LL;
    int ic = n - xr * LL;
    int shift = ic - xr + (LL - 1);
    float val = (dd < 64) ? rel_rows[shift * 64 + dd]
                          : rel_cols[shift * 64 + (dd - 64)];
    Pcatb[p] = f2bf(val);
  }
}

// x [b][c][n] fp32 -> xTb [b][n][c] bf16
__global__ __launch_bounds__(256) void transpose_x(
    const float* __restrict__ x, unsigned short* __restrict__ xTb) {
  __shared__ float t[64][65];
  const int n0 = blockIdx.x * 64;
  const int c0 = blockIdx.y * 64;
  const int b = blockIdx.z;
  const int j = threadIdx.x & 63;
  const int g = threadIdx.x >> 6;
  const float* xp = x + (size_t)b * CIN * NSP;
#pragma unroll
  for (int i = 0; i < 16; i++) {
    int cl = g * 16 + i;
    t[cl][j] = xp[(size_t)(c0 + cl) * NSP + n0 + j];
  }
  __syncthreads();
  unsigned short* op = xTb + (size_t)b * NSP * CIN;
#pragma unroll
  for (int i = 0; i < 16; i++) {
    int nl = g * 16 + i;
    op[(size_t)(n0 + nl) * CIN + c0 + j] = f2bf(t[j][nl]);
  }
}

// ---------------------------------------------------------------------------
// proj (lookahead-2, counted vmcnt): y16 = bf16(W @ xT + b); BN partials
__global__ __launch_bounds__(256) void proj_mfma(
    const unsigned short* __restrict__ Wstb, const float* __restrict__ bst,
    const unsigned short* __restrict__ xTb, unsigned short* __restrict__ y16,
    float* __restrict__ part1, float* __restrict__ part2) {
  __shared__ unsigned short As[2][8192];
  __shared__ unsigned short Bs[2][8192];
  int sw = ((blockIdx.x & 7) * 90) + (blockIdx.x >> 3);   // 720 wg
  const int rb = sw % 5;
  const int nb = (sw / 5) % 18;
  const int b = sw / 90;
  const int r0 = rb * 128;
  const int n0 = nb * 128;
  MFMA_PROLOG();
  const unsigned short* A = Wstb + (size_t)r0 * CIN;
  const unsigned short* B = xTb + (size_t)b * NSP * CIN + (size_t)n0 * CIN;

  STAGE128x64(A, CIN, As[0]);
  STAGE128x64(B, CIN, Bs[0]);
  STAGE128x64(A + 64, CIN, As[1]);
  STAGE128x64(B + 64, CIN, Bs[1]);
  asm volatile("s_waitcnt vmcnt(8)" ::: "memory");
  __builtin_amdgcn_sched_barrier(0);
  __builtin_amdgcn_s_barrier();

  int cur = 0;
  for (int t = 0; t < 8; ++t) {
    __builtin_amdgcn_s_setprio(1);
    MFMA_STEP(As[cur], Bs[cur]);
    __builtin_amdgcn_s_setprio(0);
    __builtin_amdgcn_sched_barrier(0);
    __builtin_amdgcn_s_barrier();
    if (t + 2 < 8) {
      STAGE128x64(A + (t + 2) * 64, CIN, As[cur]);
      STAGE128x64(B + (t + 2) * 64, CIN, Bs[cur]);
      asm volatile("s_waitcnt vmcnt(8)" ::: "memory");
    } else {
      asm volatile("s_waitcnt vmcnt(0)" ::: "memory");
    }
    __builtin_amdgcn_sched_barrier(0);
    __builtin_amdgcn_s_barrier();
    cur ^= 1;
  }

  float* sp = (float*)&As[0][0];   // [128][2] s1 then [128][2] s2
#pragma unroll
  for (int m = 0; m < 4; m++) {
#pragma unroll
    for (int r = 0; r < 4; r++) {
      int rl = wr * 64 + m * 16 + (lane >> 4) * 4 + r;
      int row = r0 + rl;
      float bias = bst[row];
      float s1 = 0.f, s2 = 0.f;
#pragma unroll
      for (int n = 0; n < 4; n++) {
        float yv = acc[m][n][r] + bias;
        s1 += yv;
        s2 += yv * yv;
        y16[((size_t)b * OCH + row) * NSP + n0 + wc * 64 + n * 16 + (lane & 15)] = f2bf(yv);
      }
#pragma unroll
      for (int off = 1; off < 16; off <<= 1) {
        s1 += __shfl_xor(s1, off);
        s2 += __shfl_xor(s2, off);
      }
      if ((lane & 15) == 0) {
        sp[rl * 2 + wc] = s1;
        sp[256 + rl * 2 + wc] = s2;
      }
    }
  }
  __syncthreads();
  if (tid < 128) {
    size_t pbase = ((size_t)b * 18 + nb) * OCH + r0 + tid;
    part1[pbase] = sp[tid * 2] + sp[tid * 2 + 1];
    part2[pbase] = sp[256 + tid * 2] + sp[256 + tid * 2 + 1];
  }
}

// reduce 144 partials/channel -> chanA/chanB
__global__ __launch_bounds__(256) void bn_finalize(
    const float* __restrict__ part1, const float* __restrict__ part2,
    const float* __restrict__ qs_, const float* __restrict__ qb_,
    const float* __restrict__ ks_, const float* __restrict__ kb_,
    const float* __restrict__ vs_, const float* __restrict__ vb_,
    float* __restrict__ chanA, float* __restrict__ chanB) {
  const int ch = blockIdx.x;
  const int tid = threadIdx.x;
  float s1 = 0.f, s2 = 0.f;
  for (int t = tid; t < 144; t += 256) {
    s1 += part1[(size_t)t * OCH + ch];
    s2 += part2[(size_t)t * OCH + ch];
  }
  __shared__ float sb[8];
#pragma unroll
  for (int off = 32; off > 0; off >>= 1) {
    s1 += __shfl_down(s1, off);
    s2 += __shfl_down(s2, off);
  }
  int lane = tid & 63, wid = tid >> 6;
  if (lane == 0) { sb[wid] = s1; sb[4 + wid] = s2; }
  __syncthreads();
  if (tid == 0) {
    float ts  = sb[0] + sb[1] + sb[2] + sb[3];
    float ts2 = sb[4] + sb[5] + sb[6] + sb[7];
    const float inv = 1.f / (float)(BB * NSP);
    float mean = ts * inv;
    float var  = ts2 * inv - mean * mean;
    float scale, bias;
    if (ch < 64)       { scale = qs_[ch];       bias = qb_[ch]; }
    else if (ch < 128) { scale = ks_[ch - 64];  bias = kb_[ch - 64]; }
    else               { scale = vs_[ch - 128]; bias = vb_[ch - 128]; }
    float a = scale * rsqrtf(var + 1e-5f);
    chanA[ch] = a;
    chanB[ch] = bias - mean * a;
  }
}

// in-place affine+relu on all of y16 (bf16)
__global__ __launch_bounds__(256) void bnrelu_all(
    unsigned short* __restrict__ y16, const float* __restrict__ chanA,
    const float* __restrict__ chanB) {
  size_t i = ((size_t)blockIdx.x * 256 + threadIdx.x) * 8;
  int ch = (int)((i / NSP) % OCH);
  float a = chanA[ch], bo = chanB[ch];
  ushort4 u0 = *(ushort4*)&y16[i];
  ushort4 u1 = *(ushort4*)&y16[i + 4];
  ushort4 o0, o1;
  o0.x = f2bf(fmaxf(0.f, a * bf2f(u0.x) + bo));
  o0.y = f2bf(fmaxf(0.f, a * bf2f(u0.y) + bo));
  o0.z = f2bf(fmaxf(0.f, a * bf2f(u0.z) + bo));
  o0.w = f2bf(fmaxf(0.f, a * bf2f(u0.w) + bo));
  o1.x = f2bf(fmaxf(0.f, a * bf2f(u1.x) + bo));
  o1.y = f2bf(fmaxf(0.f, a * bf2f(u1.y) + bo));
  o1.z = f2bf(fmaxf(0.f, a * bf2f(u1.z) + bo));
  o1.w = f2bf(fmaxf(0.f, a * bf2f(u1.w) + bo));
  *(ushort4*)&y16[i] = o0;
  *(ushort4*)&y16[i + 4] = o1;
}

// q/k channels [d][n] -> qTb/kTb [n][d], LDS-tiled, post-relu
__global__ __launch_bounds__(256) void tr_qk(
    const unsigned short* __restrict__ y16, unsigned short* __restrict__ qTb,
    unsigned short* __restrict__ kTb) {
  __shared__ unsigned short t[64][72];
  const int n0 = blockIdx.x * 64;
  const int qk = blockIdx.y;          // 0=q, 1=k
  const int b = blockIdx.z;
  const int j = threadIdx.x & 63;
  const int g = threadIdx.x >> 6;
#pragma unroll
  for (int i = 0; i < 16; i++) {
    int cl = g * 16 + i;
    t[cl][j] = y16[((size_t)b * OCH + qk * 64 + cl) * NSP + n0 + j];
  }
  __syncthreads();
  unsigned short* out = (qk == 0) ? qTb : kTb;
#pragma unroll
  for (int i = 0; i < 16; i++) {
    int nl = g * 16 + i;
    out[((size_t)b * NSP + n0 + nl) * 64 + j] = t[j][nl];
  }
}

// qs[b,d] = sum_n q[b,d,n] (post-relu, from y16)
__global__ __launch_bounds__(256) void qsum_kernel(
    const unsigned short* __restrict__ y16, float* __restrict__ qs) {
  int bd = blockIdx.x;
  int b = bd >> 6, d = bd & 63;
  const ushort4* p = (const ushort4*)(y16 + ((size_t)b * OCH + d) * NSP);
  float s = 0.f;
  for (int t = threadIdx.x; t < NSP / 4; t += 256) {
    ushort4 u = p[t];
    s += bf2f(u.x) + bf2f(u.y) + bf2f(u.z) + bf2f(u.w);
  }
  __shared__ float sb[4];
#pragma unroll
  for (int off = 32; off > 0; off >>= 1) s += __shfl_down(s, off);
  int lane = threadIdx.x & 63, wid = threadIdx.x >> 6;
  if (lane == 0) sb[wid] = s;
  __syncthreads();
  if (threadIdx.x == 0) qs[bd] = sb[0] + sb[1] + sb[2] + sb[3];
}

// Gqp[b*4+kc][d][e] = partial sum over k-chunk of q[d,i]*q[e,i]
__global__ __launch_bounds__(256) void gq_mfma(
    const unsigned short* __restrict__ y16, float* __restrict__ Gqp) {
  __shared__ float wlds[4 * 4096];
  const int bx = blockIdx.x;          // 32
  const int b = bx >> 2, kc = bx & 3;
  const int tid = threadIdx.x;
  const int lane = tid & 63;
  const int w = tid >> 6;
  const unsigned short* q = y16 + (size_t)b * OCH * NSP;
  f32x4 acc[4][4] = {};
  for (int k0 = kc * 576 + w * 32; k0 < (kc + 1) * 576; k0 += 128) {
    bf16x8 fr[4];
#pragma unroll
    for (int f = 0; f < 4; f++) {
      int row = f * 16 + (lane & 15);
      fr[f] = *(const bf16x8*)&q[(size_t)row * NSP + k0 + (lane >> 4) * 8];
    }
#pragma unroll
    for (int fm = 0; fm < 4; fm++)
#pragma unroll
      for (int fn = 0; fn < 4; fn++)
        acc[fm][fn] = __builtin_amdgcn_mfma_f32_16x16x32_bf16(
            fr[fm], fr[fn], acc[fm][fn], 0, 0, 0);
  }
#pragma unroll
  for (int fm = 0; fm < 4; fm++)
#pragma unroll
    for (int fn = 0; fn < 4; fn++)
#pragma unroll
      for (int r = 0; r < 4; r++) {
        int d = fm * 16 + (lane >> 4) * 4 + r;
        int e = fn * 16 + (lane & 15);
        wlds[w * 4096 + d * 64 + e] = acc[fm][fn][r];
      }
  __syncthreads();
  for (int t = tid; t < 4096; t += 256)
    Gqp[(size_t)bx * 4096 + t] =
        wlds[t] + wlds[4096 + t] + wlds[8192 + t] + wlds[12288 + t];
}

// ---------------------------------------------------------------------------
// energy+exp: Pp = bf16(exp(qT·kT^T)) + per-row partial sums
__global__ __launch_bounds__(256) void energy_mfma(
    const unsigned short* __restrict__ qTb, const unsigned short* __restrict__ kTb,
    unsigned short* __restrict__ Pp, float* __restrict__ Ppart) {
  __shared__ unsigned short As[8192];
  __shared__ unsigned short Bs[8192];
  int sw = ((blockIdx.x & 7) * 324) + (blockIdx.x >> 3);   // 2592 wg
  const int jb = sw % 18;
  const int ib = (sw / 18) % 18;
  const int b = sw / 324;
  const int i0 = ib * 128;
  const int j0 = jb * 128;
  MFMA_PROLOG();
  STAGE128x64(qTb + ((size_t)b * NSP + i0) * 64, 64, As);
  STAGE128x64(kTb + ((size_t)b * NSP + j0) * 64, 64, Bs);
  __syncthreads();
  MFMA_STEP(As, Bs);
  __syncthreads();
  float* sp = (float*)As;
  unsigned short* pp = Pp + (size_t)b * NSP * NSP;
#pragma unroll
  for (int m = 0; m < 4; m++) {
#pragma unroll
    for (int r = 0; r < 4; r++) {
      int rl = wr * 64 + m * 16 + (lane >> 4) * 4 + r;
      int i = i0 + rl;
      float s1 = 0.f;
#pragma unroll
      for (int n = 0; n < 4; n++) {
        int j = j0 + wc * 64 + n * 16 + (lane & 15);
        unsigned short h = f2bf(__expf(acc[m][n][r]));
        pp[(size_t)i * NSP + j] = h;
        s1 += bf2f(h);
      }
#pragma unroll
      for (int off = 1; off < 16; off <<= 1) s1 += __shfl_xor(s1, off);
      if ((lane & 15) == 0) sp[rl * 2 + wc] = s1;
    }
  }
  __syncthreads();
  if (tid < 128)
    Ppart[((size_t)b * 18 + jb) * NSP + i0 + tid] = sp[tid * 2] + sp[tid * 2 + 1];
}

// rZ[row] = 1/sum_jb Ppart
__global__ __launch_bounds__(256) void zred_kernel(
    const float* __restrict__ Ppart, float* __restrict__ rZ) {
  int row = blockIdx.x * 256 + threadIdx.x;   // B*NSP
  int b = row / NSP, i = row % NSP;
  float s = 0.f;
#pragma unroll
  for (int jb = 0; jb < 18; jb++) s += Ppart[((size_t)b * 18 + jb) * NSP + i];
  rZ[row] = 1.f / s;
}

// ---------------------------------------------------------------------------
// Upart (lookahead-2, counted vmcnt)
__global__ __launch_bounds__(256) void up_mfma(
    const unsigned short* __restrict__ y16, const unsigned short* __restrict__ Pcatb,
    float* __restrict__ Upart) {
  __shared__ unsigned short As[2][8192];
  __shared__ unsigned short Bs[2][8192];
  int sw = ((blockIdx.x & 7) * 24) + (blockIdx.x >> 3);   // 192 wg
  const int cb = sw % 4;
  const int kc = (sw / 4) % 6;
  const int b = sw / 24;
  const int c0 = cb * 128;
  MFMA_PROLOG();
  const unsigned short* A = y16 + ((size_t)b * OCH + 128 + c0) * NSP + kc * 384;
  const unsigned short* B = Pcatb + kc * 384;

  STAGE128x64(A, NSP, As[0]);
  STAGE128x64(B, NSP, Bs[0]);
  STAGE128x64(A + 64, NSP, As[1]);
  STAGE128x64(B + 64, NSP, Bs[1]);
  asm volatile("s_waitcnt vmcnt(8)" ::: "memory");
  __builtin_amdgcn_sched_barrier(0);
  __builtin_amdgcn_s_barrier();

  int cur = 0;
  for (int t = 0; t < 6; ++t) {
    __builtin_amdgcn_s_setprio(1);
    MFMA_STEP(As[cur], Bs[cur]);
    __builtin_amdgcn_s_setprio(0);
    __builtin_amdgcn_sched_barrier(0);
    __builtin_amdgcn_s_barrier();
    if (t + 2 < 6) {
      STAGE128x64(A + (t + 2) * 64, NSP, As[cur]);
      STAGE128x64(B + (t + 2) * 64, NSP, Bs[cur]);
      asm volatile("s_waitcnt vmcnt(8)" ::: "memory");
    } else {
      asm volatile("s_waitcnt vmcnt(0)" ::: "memory");
    }
    __builtin_amdgcn_sched_barrier(0);
    __builtin_amdgcn_s_barrier();
    cur ^= 1;
  }

  float* up = Upart + ((size_t)kc * BB + b) * CIN * 128 + (size_t)c0 * 128;
#pragma unroll
  for (int m = 0; m < 4; m++)
#pragma unroll
    for (int r = 0; r < 4; r++) {
      int rl = wr * 64 + m * 16 + (lane >> 4) * 4 + r;
#pragma unroll
      for (int n = 0; n < 4; n++) {
        int col = wc * 64 + n * 16 + (lane & 15);
        up[(size_t)rl * 128 + col] = acc[m][n][r];
      }
    }
}

// merged: up_reduce + rel_stats + combine_u. one block per channel c.
__global__ __launch_bounds__(256) void rel_finalize(
    const float* __restrict__ Upart, const float* __restrict__ Gqp,
    const float* __restrict__ qs,
    const float* __restrict__ bnr_s, const float* __restrict__ bnr_b,
    const float* __restrict__ bnc_s, const float* __restrict__ bnc_b,
    float* __restrict__ offc, unsigned short* __restrict__ Ucb) {
  const int c = blockIdx.x;        // 512
  const int tid = threadIdx.x;
  __shared__ float U[8][128];      // [b][dd]: 0:64=h, 64:128=w
  __shared__ float ghw[2];
  // phase A: reduce Upart over kc chunks
  for (int t = tid; t < 1024; t += 256) {
    int b = t >> 7, dd = t & 127;
    float s = 0.f;
#pragma unroll
    for (int kc = 0; kc < 6; kc++)
      s += Upart[(((size_t)kc * BB + b) * CIN + c) * 128 + dd];
    U[b][dd] = s;
  }
  __syncthreads();
  // phase B: closed-form BN stats (threads 0-63 = d)
  if (tid < 64) {
    const int d = tid;
    float s1h = 0.f, s2h = 0.f, s1w = 0.f, s2w = 0.f;
    for (int b = 0; b < BB; b++) {
      float uh = U[b][d], uw = U[b][64 + d];
      float th = 0.f, tw = 0.f;
#pragma unroll
      for (int kc = 0; kc < 4; kc++) {
        const float* G = Gqp + ((size_t)(b * 4 + kc)) * 4096 + d * 64;
        for (int e = 0; e < 64; e++) {
          float g = G[e];
          th += g * U[b][e];
          tw += g * U[b][64 + e];
        }
      }
      float qsd = qs[b * 64 + d];
      s1h += uh * qsd;
      s2h += uh * th;
      s1w += uw * qsd;
      s2w += uw * tw;
    }
#pragma unroll
    for (int off = 32; off > 0; off >>= 1) {
      s1h += __shfl_down(s1h, off);
      s2h += __shfl_down(s2h, off);
      s1w += __shfl_down(s1w, off);
      s2w += __shfl_down(s2w, off);
    }
    if (d == 0) {
      const float inv = 1.f / (float)(BB * NSP);
      float mh = s1h * inv, vh = s2h * inv - mh * mh;
      float mw = s1w * inv, vw = s2w * inv - mw * mw;
      float gch = bnr_s[c] * rsqrtf(vh + 1e-5f);
      float gcw = bnc_s[c] * rsqrtf(vw + 1e-5f);
      ghw[0] = gch;
      ghw[1] = gcw;
      offc[c] = (bnr_b[c] - mh * gch) + (bnc_b[c] - mw * gcw);
    }
  }
  __syncthreads();
  // phase C: Ucb[b][c][d] = bf16(uh*gh + uw*gw)
  for (int t = tid; t < 512; t += 256) {
    int b = t >> 6, d = t & 63;
    Ucb[((size_t)b * CIN + c) * 64 + d] =
        f2bf(U[b][d] * ghw[0] + U[b][64 + d] * ghw[1]);
  }
}

// ---------------------------------------------------------------------------
// fused (512 threads, 8 waves 2x4, lookahead-2 counted vmcnt(4), T2, T5):
// dst[c,i] = gamma*( rZ[i]*sum_j v[c,j]*Pp[i,j] + sum_d Ucb[c,d]*qT[i,d]
//                  + offc[c] ) + x[c,i]
__global__ __launch_bounds__(512) void attn_fused_gemm(
    const unsigned short* __restrict__ y16,   // v at channel offset 128
    const unsigned short* __restrict__ Pp,
    const float* __restrict__ rZ,
    const unsigned short* __restrict__ Ucb,
    const unsigned short* __restrict__ qTb,
    const float* __restrict__ offc,
    const float* __restrict__ gammap,
    const float* __restrict__ x,
    float* __restrict__ dst) {
  __shared__ unsigned short As[2][8192];
  __shared__ unsigned short Bs[2][8192];
  int sw = ((blockIdx.x & 7) * 72) + (blockIdx.x >> 3);   // 576 wg
  const int cb = sw % 4;
  const int ib = (sw / 4) % 18;
  const int b = sw / 72;
  const int c0 = cb * 128;
  const int i0 = ib * 128;
  const int tid = threadIdx.x;
  const int lane = tid & 63;
  const int w = tid >> 6;              // 0..7
  const int wr = w >> 2, wc = w & 3;   // 2x4 wave grid; 64 rows x 32 cols each
  const int rsub = lane >> 3;
  const int scolb = ((lane & 7) ^ rsub) * 8;
  f32x4 acc[4][2] = {};

  const unsigned short* A = y16 + ((size_t)b * OCH + 128 + c0) * NSP;
  const unsigned short* B = Pp + (size_t)b * NSP * NSP + (size_t)i0 * NSP;
  const unsigned short* A2 = Ucb + (size_t)b * CIN * 64 + (size_t)c0 * 64;
  const unsigned short* B2 = qTb + (size_t)b * NSP * 64 + (size_t)i0 * 64;

  // prologue: stage tiles 0 and 1 (4 loads per wave each)
  STAGE8(A, NSP, As[0], B, NSP, Bs[0]);
  STAGE8(A + 64, NSP, As[1], B + 64, NSP, Bs[1]);
  asm volatile("s_waitcnt vmcnt(4)" ::: "memory");   // tile 0 landed
  __builtin_amdgcn_sched_barrier(0);
  __builtin_amdgcn_s_barrier();

  int cur = 0;
  // tiles 0..35 = main K (Pp), tile 36 = rank-64 rel tile
  for (int tt = 0; tt < 37; ++tt) {
    if (tt == 36) {
      // softmax normalization applies only to the V*P' accumulation
#pragma unroll
      for (int n = 0; n < 2; n++) {
        float rz = rZ[(size_t)b * NSP + i0 + wc * 32 + n * 16 + (lane & 15)];
#pragma unroll
        for (int m = 0; m < 4; m++)
#pragma unroll
          for (int r = 0; r < 4; r++) acc[m][n][r] *= rz;
      }
    }
    __builtin_amdgcn_s_setprio(1);
    MFMA_STEP8(As[cur], Bs[cur]);
    __builtin_amdgcn_s_setprio(0);
    __builtin_amdgcn_sched_barrier(0);
    __builtin_amdgcn_s_barrier();                    // reads of buf[cur] done
    if (tt + 2 < 36) {
      STAGE8(A + (tt + 2) * 64, NSP, As[cur], B + (tt + 2) * 64, NSP, Bs[cur]);
      asm volatile("s_waitcnt vmcnt(4)" ::: "memory");   // tile tt+1 landed
    } else if (tt + 2 == 36) {
      STAGE8(A2, 64, As[cur], B2, 64, Bs[cur]);
      asm volatile("s_waitcnt vmcnt(4)" ::: "memory");
    } else {
      asm volatile("s_waitcnt vmcnt(0)" ::: "memory");   // tail drain
    }
    __builtin_amdgcn_sched_barrier(0);
    __builtin_amdgcn_s_barrier();                    // buf[cur^1] ready for all
    cur ^= 1;
  }

  const float gmm = gammap[0];
  const float* xp = x + (size_t)b * CIN * NSP;
  float* dp = dst + (size_t)b * CIN * NSP;
#pragma unroll
  for (int m = 0; m < 4; m++) {
#pragma unroll
    for (int r = 0; r < 4; r++) {
      int c = c0 + wr * 64 + m * 16 + (lane >> 4) * 4 + r;
      float off = offc[c];
#pragma unroll
      for (int n = 0; n < 2; n++) {
        int i = i0 + wc * 32 + n * 16 + (lane & 15);
        size_t o = (size_t)c * NSP + i;
        dp[o] = gmm * (acc[m][n][r] + off) + xp[o];
      }
    }
  }
}

// ---------------------------------------------------------------------------
extern "C" void kernel_launch(void* const* d_in, const int* in_sizes, int n_in,
                              void* d_out, int out_size, void* d_ws, size_t ws_size,
                              hipStream_t stream) {
  const float* x        = (const float*)d_in[0];
  const float* Wq       = (const float*)d_in[1];
  const float* bq       = (const float*)d_in[2];
  const float* q_scale  = (const float*)d_in[3];
  const float* q_bias   = (const float*)d_in[4];
  const float* Wk       = (const float*)d_in[5];
  const float* bk       = (const float*)d_in[6];
  const float* k_scale  = (const float*)d_in[7];
  const float* k_bias   = (const float*)d_in[8];
  const float* Wv       = (const float*)d_in[9];
  const float* bv       = (const float*)d_in[10];
  const float* v_scale  = (const float*)d_in[11];
  const float* v_bias   = (const float*)d_in[12];
  const float* rel_rows = (const float*)d_in[13];
  const float* rel_cols = (const float*)d_in[14];
  const float* bnr_s    = (const float*)d_in[15];
  const float* bnr_b    = (const float*)d_in[16];
  const float* bnc_s    = (const float*)d_in[17];
  const float* bnc_b    = (const float*)d_in[18];
  const float* gamma    = (const float*)d_in[19];
  float* dst = (float*)d_out;

  float* ws = (float*)d_ws;
  size_t o = 0;
  unsigned short* Wstb = (unsigned short*)(ws + o); o += (size_t)OCH * CIN / 2;
  float* bst    = ws + o; o += 1024;
  float* chanA  = ws + o; o += 1024;
  float* chanB  = ws + o; o += 1024;
  unsigned short* Pcatb = (unsigned short*)(ws + o); o += (size_t)128 * NSP / 2;
  unsigned short* y16 = (unsigned short*)(ws + o); o += (size_t)BB * OCH * NSP / 2;
  unsigned short* xTb = (unsigned short*)(ws + o); o += (size_t)BB * NSP * CIN / 2;
  unsigned short* Pp  = (unsigned short*)(ws + o); o += (size_t)BB * NSP * NSP / 2;
  float* Ppart  = ws + o; o += (size_t)BB * 18 * NSP;
  float* rZ     = ws + o; o += (size_t)BB * NSP;
  float* Upart  = ws + o; o += (size_t)6 * BB * CIN * 128;
  float* Gqp    = ws + o; o += (size_t)32 * 4096;
  float* part1  = ws + o; o += (size_t)BB * 18 * OCH;
  float* part2  = ws + o; o += (size_t)BB * 18 * OCH;
  float* qs     = ws + o; o += 1024;
  float* offc   = ws + o; o += 1024;
  unsigned short* qTb = (unsigned short*)(ws + o); o += (size_t)BB * NSP * 64 / 2;
  unsigned short* kTb = (unsigned short*)(ws + o); o += (size_t)BB * NSP * 64 / 2;
  unsigned short* Ucb = (unsigned short*)(ws + o); o += (size_t)BB * CIN * 64 / 2;

  prep_all<<<(OCH * CIN + 128 * NSP) / 256, 256, 0, stream>>>(
      Wq, bq, Wk, bk, Wv, bv, rel_rows, rel_cols, Wstb, bst, Pcatb);
  transpose_x<<<dim3(NSP / 64, CIN / 64, BB), 256, 0, stream>>>(x, xTb);

  proj_mfma<<<720, 256, 0, stream>>>(Wstb, bst, xTb, y16, part1, part2);
  bn_finalize<<<OCH, 256, 0, stream>>>(part1, part2, q_scale, q_bias, k_scale,
                                       k_bias, v_scale, v_bias, chanA, chanB);
  bnrelu_all<<<(int)((size_t)BB * OCH * NSP / 8 / 256), 256, 0, stream>>>(y16, chanA, chanB);
  tr_qk<<<dim3(NSP / 64, 2, BB), 256, 0, stream>>>(y16, qTb, kTb);
  qsum_kernel<<<BB * 64, 256, 0, stream>>>(y16, qs);
  gq_mfma<<<32, 256, 0, stream>>>(y16, Gqp);

  energy_mfma<<<2592, 256, 0, stream>>>(qTb, kTb, Pp, Ppart);
  zred_kernel<<<BB * NSP / 256, 256, 0, stream>>>(Ppart, rZ);

  up_mfma<<<192, 256, 0, stream>>>(y16, Pcatb, Upart);
  rel_finalize<<<CIN, 256, 0, stream>>>(Upart, Gqp, qs, bnr_s, bnr_b,
                                        bnc_s, bnc_b, offc, Ucb);

  attn_fused_gemm<<<576, 512, 0, stream>>>(y16, Pp, rZ, Ucb, qTb, offc, gamma, x, dst);
}